// Round 5
// baseline (2618.394 us; speedup 1.0000x reference)
//
#include <hip/hip_runtime.h>

// Problem constants
#define NB    16
#define NT    3
#define NCTX  2048
#define NLAT  512
#define DIMV  512
#define HALFD 256
#define NFEAT 51
#define NBT   48
#define MROWS 24576    // NBT*NLAT
#define GRP   4        // bt per context group
#define NGRP  12
#define GROWS 8192     // GRP*NCTX

typedef unsigned short bfu;   // bf16 storage as raw bits
typedef short bf16x8 __attribute__((ext_vector_type(8)));   // 8 bf16 = 4 VGPR
typedef float f32x4  __attribute__((ext_vector_type(4)));   // MFMA 16x16 acc
typedef float f32x2  __attribute__((ext_vector_type(2)));   // packed fp32 pair

__device__ __forceinline__ float bf2f(bfu u){ return __uint_as_float(((unsigned int)u) << 16); }
__device__ __forceinline__ bfu f2bf(float f){
  unsigned int u = __float_as_uint(f);
  u += 0x7FFFu + ((u >> 16) & 1u);          // RNE
  return (bfu)(u >> 16);
}
__device__ __forceinline__ float loadE(const float* p){ return *p; }
__device__ __forceinline__ float loadE(const bfu* p){ return bf2f(*p); }
__device__ __forceinline__ void storeE(float* p, float v){ *p = v; }
__device__ __forceinline__ void storeE(bfu* p, float v){ *p = f2bf(v); }
__device__ __forceinline__ bfu to_bfu(float f){ return f2bf(f); }
__device__ __forceinline__ bfu to_bfu(bfu u){ return u; }

// ---------------------------------------------------------------------------
// FPS, wave-synchronous, register-resident. One 64-lane wave per batch.
// Coords+dist live in VGPRs as float2 pairs (launch_bounds(64,1) -> no spill);
// packed fp32 math with contraction OFF keeps numpy bit-exactness
// (((dx^2+dy^2)+dz^2), first-occurrence argmax). 4 independent scan chains
// cut the serial cndmask chain; 6-step xor butterfly for the wave argmax.
// ---------------------------------------------------------------------------
__global__ __launch_bounds__(64, 1) void fps_kernel(const float* __restrict__ pc,
                                                    int* __restrict__ idx_out){
#pragma clang fp contract(off)
  __shared__ float4 c4[NCTX];
  const int b = blockIdx.x, lane = threadIdx.x;
  const float* src = pc + (size_t)b * (NT * NCTX * 3);

  f32x2 px[16], py[16], pz[16], dist[16];
  #pragma unroll
  for (int p = 0; p < 16; ++p){
    const int i0 = lane + (p << 7);     // point j = 2p
    const int i1 = i0 + 64;             // point j = 2p+1
    const float x0 = src[i0*3+0], y0 = src[i0*3+1], z0 = src[i0*3+2];
    const float x1 = src[i1*3+0], y1 = src[i1*3+1], z1 = src[i1*3+2];
    px[p][0] = x0; px[p][1] = x1;
    py[p][0] = y0; py[p][1] = y1;
    pz[p][0] = z0; pz[p][1] = z1;
    dist[p][0] = 1e10f; dist[p][1] = 1e10f;
    c4[i0] = make_float4(x0, y0, z0, 0.f);
    c4[i1] = make_float4(x1, y1, z1, 0.f);
  }
  if (lane == 0) idx_out[b * NLAT] = 0;
  __syncthreads();

  int last = 0;
  for (int step = 1; step < NLAT; ++step){
    const float4 lc = c4[last];                    // uniform addr -> broadcast
    f32x2 L0; L0[0] = lc.x; L0[1] = lc.x;
    f32x2 L1; L1[0] = lc.y; L1[1] = lc.y;
    f32x2 L2; L2[0] = lc.z; L2[1] = lc.z;

    float bv[4] = {-1.f, -1.f, -1.f, -1.f};
    int   bi[4] = {0, 0, 0, 0};
    #pragma unroll
    for (int p = 0; p < 16; ++p){
      const int c = p >> 2;                        // 4 independent chains
      const f32x2 dx = px[p] - L0;
      const f32x2 dy = py[p] - L1;
      const f32x2 dz = pz[p] - L2;
      const f32x2 d  = (dx*dx + dy*dy) + dz*dz;    // contract(off): exact numpy
      f32x2 nd;
      nd[0] = fminf(dist[p][0], d[0]);
      nd[1] = fminf(dist[p][1], d[1]);
      dist[p] = nd;
      const int i0 = lane + (p << 7);
      if (nd[0] > bv[c]){ bv[c] = nd[0]; bi[c] = i0; }        // ascending idx
      if (nd[1] > bv[c]){ bv[c] = nd[1]; bi[c] = i0 + 64; }
    }
    // merge chains (chain c covers strictly ascending index ranges -> strict >)
    if (bv[1] > bv[0]){ bv[0] = bv[1]; bi[0] = bi[1]; }
    if (bv[3] > bv[2]){ bv[2] = bv[3]; bi[2] = bi[3]; }
    if (bv[2] > bv[0]){ bv[0] = bv[2]; bi[0] = bi[2]; }

    float v = bv[0]; int i = bi[0];
    #pragma unroll
    for (int off = 1; off < 64; off <<= 1){
      const float ov = __shfl_xor(v, off, 64);
      const int   oi = __shfl_xor(i, off, 64);
      if (ov > v || (ov == v && oi < i)){ v = ov; i = oi; }
    }
    last = i;                                      // all lanes agree
    if (lane == 0) idx_out[b * NLAT + step] = i;
  }
}

// ---------------------------------------------------------------------------
// Fused (gather) + point_embed x2 + layernorm -> bf16. 16 points / block.
// ---------------------------------------------------------------------------
template<bool GATHER, bool WRITE_EMB>
__global__ __launch_bounds__(256) void embed_kernel(
    const float* __restrict__ pc, const float* __restrict__ pc2,
    const int* __restrict__ idx,
    const float* __restrict__ basis, const float* __restrict__ pe_w,
    const float* __restrict__ pe_b,
    const float* __restrict__ ln_g, const float* __restrict__ ln_b,
    bfu* __restrict__ emb, bfu* __restrict__ lnout, int nppbt)
{
  __shared__ float feat[2][16][NFEAT + 1];
  __shared__ float outb[16][DIMV];
  const int tid = threadIdx.x;
  const int p0 = blockIdx.x << 4;

  if (tid < 32){
    const int s = tid >> 4, p = tid & 15;
    const int gp = p0 + p;
    const int bt = gp / nppbt;
    const int n  = gp - bt * nppbt;
    const int bb = bt / NT;
    const int srcn = GATHER ? idx[bb * NLAT + n] : n;
    const float* sp = (s ? pc2 : pc) + ((size_t)bt * NCTX + srcn) * 3;
    const float x0 = sp[0], x1 = sp[1], x2 = sp[2];
    #pragma unroll
    for (int e = 0; e < 24; ++e){
      const float pr = __fadd_rn(__fadd_rn(__fmul_rn(x0, basis[e]),
                                           __fmul_rn(x1, basis[24 + e])),
                                 __fmul_rn(x2, basis[48 + e]));
      feat[s][p][e]      = sinf(pr);
      feat[s][p][24 + e] = cosf(pr);
    }
    feat[s][p][48] = x0; feat[s][p][49] = x1; feat[s][p][50] = x2;
  }
  __syncthreads();

  {
    float w[NFEAT];
    #pragma unroll
    for (int k = 0; k < NFEAT; ++k) w[k] = pe_w[k * HALFD + tid];
    const float bv = pe_b[tid];
    #pragma unroll
    for (int half = 0; half < 2; ++half){
      for (int p = 0; p < 16; ++p){
        float acc = bv;
        #pragma unroll
        for (int k = 0; k < NFEAT; ++k) acc = fmaf(feat[half][p][k], w[k], acc);
        outb[p][half * HALFD + tid] = acc;
      }
    }
  }
  __syncthreads();

  const int lane = tid & 63, wv = tid >> 6;
  for (int pp = 0; pp < 4; ++pp){
    const int p = (wv << 2) + pp;
    const size_t gp = (size_t)p0 + p;
    float x[8];
    #pragma unroll
    for (int j = 0; j < 8; ++j) x[j] = outb[p][lane + (j << 6)];
    float s = 0.f;
    #pragma unroll
    for (int j = 0; j < 8; ++j) s += x[j];
    for (int o = 32; o; o >>= 1) s += __shfl_xor(s, o, 64);
    const float m = s * (1.0f / 512.0f);
    float s2 = 0.f;
    #pragma unroll
    for (int j = 0; j < 8; ++j){ const float d = x[j] - m; s2 = fmaf(d, d, s2); }
    for (int o = 32; o; o >>= 1) s2 += __shfl_xor(s2, o, 64);
    const float inv = 1.0f / sqrtf(s2 * (1.0f / 512.0f) + 1e-5f);
    #pragma unroll
    for (int j = 0; j < 8; ++j){
      const int c = lane + (j << 6);
      const float r = (x[j] - m) * inv * ln_g[c] + ln_b[c];
      const size_t o2 = gp * DIMV + c;
      if (WRITE_EMB) emb[o2] = f2bf(x[j]);
      lnout[o2] = f2bf(r);
    }
  }
}

// ---------------------------------------------------------------------------
// Tiled transpose: in [R][C] (fp32 or bf16) -> out bf16 [C][R]. 32x32 tiles.
// ---------------------------------------------------------------------------
template<typename TIN>
__global__ __launch_bounds__(256) void transp_kernel(
    const TIN* __restrict__ in, bfu* __restrict__ out, int R, int C,
    long long sIn, long long sOut)
{
  __shared__ bfu t[32][33];
  in  += (size_t)blockIdx.z * sIn;
  out += (size_t)blockIdx.z * sOut;
  const int c0 = blockIdx.x * 32, r0 = blockIdx.y * 32;
  const int tx = threadIdx.x & 31, ty = threadIdx.x >> 5;
  #pragma unroll
  for (int rr = ty; rr < 32; rr += 8)
    t[rr][tx] = to_bfu(in[(size_t)(r0 + rr) * C + c0 + tx]);
  __syncthreads();
  #pragma unroll
  for (int rr = ty; rr < 32; rr += 8)
    out[(size_t)(c0 + rr) * R + r0 + tx] = t[tx][rr];
}

// ---------------------------------------------------------------------------
// MFMA GEMM: C[M][N] = A[M][K] * B[N][K]^T, all bf16 inputs.
// 128x128 block tile, 4 waves (2x2), each wave 64x64 = 4x4 MFMA 16x16x32.
// LDS rows padded to 40 shorts (80 B = 20 banks -> 2-way max conflicts).
// ---------------------------------------------------------------------------
#define EPI_NONE     0
#define EPI_SPLIT    1
#define EPI_SCALE    2
#define EPI_BIAS_RES 3
#define LDST 40

template<typename TC, typename TR, int EPI>
__global__ __launch_bounds__(256, 2) void gemm_mfma(
    const bfu* __restrict__ A, const bfu* __restrict__ B,
    TC* __restrict__ C, TC* __restrict__ C2,
    const float* __restrict__ bias, const TR* __restrict__ res,
    float scale, int N, int K, int lda, int ldb, int ldc,
    long long sA, long long sB, long long sC)
{
  const int bz = blockIdx.z;
  A += (size_t)bz * sA;
  B += (size_t)bz * sB;
  const size_t coff = (size_t)bz * sC;

  __shared__ __align__(16) short As[128 * LDST];
  __shared__ __align__(16) short Bs[128 * LDST];

  const int tid = threadIdx.x;
  const int lane = tid & 63, w = tid >> 6;
  const int m0 = blockIdx.y * 128, n0 = blockIdx.x * 128;
  const int wm = (w & 1) * 64, wn = (w >> 1) * 64;
  const int fr = lane & 15, quad = lane >> 4;

  f32x4 acc[4][4];
  #pragma unroll
  for (int i = 0; i < 4; ++i)
    #pragma unroll
    for (int j = 0; j < 4; ++j)
      #pragma unroll
      for (int r = 0; r < 4; ++r) acc[i][j][r] = 0.f;

  for (int k0 = 0; k0 < K; k0 += 32){
    #pragma unroll
    for (int i = 0; i < 2; ++i){
      const int ch = tid + 256 * i;             // 512 16B-chunks per tile
      const int r = ch >> 2, c = ch & 3;
      *(uint4*)&As[r * LDST + c * 8] =
          *(const uint4*)(A + (size_t)(m0 + r) * lda + k0 + c * 8);
      *(uint4*)&Bs[r * LDST + c * 8] =
          *(const uint4*)(B + (size_t)(n0 + r) * ldb + k0 + c * 8);
    }
    __syncthreads();
    bf16x8 af[4], bf[4];
    #pragma unroll
    for (int i = 0; i < 4; ++i)
      af[i] = *(const bf16x8*)&As[(wm + i * 16 + fr) * LDST + quad * 8];
    #pragma unroll
    for (int j = 0; j < 4; ++j)
      bf[j] = *(const bf16x8*)&Bs[(wn + j * 16 + fr) * LDST + quad * 8];
    #pragma unroll
    for (int i = 0; i < 4; ++i)
      #pragma unroll
      for (int j = 0; j < 4; ++j)
        acc[i][j] = __builtin_amdgcn_mfma_f32_16x16x32_bf16(af[i], bf[j], acc[i][j], 0, 0, 0);
    __syncthreads();
  }

  // C/D layout: col = lane&15, row = quad*4 + reg
  TC* Cp = C + coff;
  #pragma unroll
  for (int i = 0; i < 4; ++i){
    #pragma unroll
    for (int r = 0; r < 4; ++r){
      const int cm = m0 + wm + i * 16 + quad * 4 + r;
      #pragma unroll
      for (int j = 0; j < 4; ++j){
        const int cn = n0 + wn + j * 16 + fr;
        float v = acc[i][j][r];
        if (EPI == EPI_SCALE)    v *= scale;
        if (EPI == EPI_BIAS_RES) v = v + bias[cn] + loadE(&res[coff + (size_t)cm * ldc + cn]);
        if (EPI == EPI_SPLIT){
          const int half = N >> 1;
          if (cn < half) storeE(&C [(size_t)cm * half + cn],          v);
          else           storeE(&C2[(size_t)cm * half + (cn - half)], v);
        } else {
          storeE(&Cp[(size_t)cm * ldc + cn], v);
        }
      }
    }
  }
}

// ---------------------------------------------------------------------------
// Fused MLP1 + exact GeLU (MFMA): act = (A@w1T[a]+b1a) * gelu(A@w1T[g]+b1g).
// ---------------------------------------------------------------------------
__global__ __launch_bounds__(256, 1) void mlp1_mfma(
    const bfu* __restrict__ A, const bfu* __restrict__ B,  // B = w1T [4096][512]
    const float* __restrict__ b1, bfu* __restrict__ act)
{
  __shared__ __align__(16) short As[128 * LDST];
  __shared__ __align__(16) short Ba[128 * LDST];
  __shared__ __align__(16) short Bg[128 * LDST];

  const int tid = threadIdx.x;
  const int lane = tid & 63, w = tid >> 6;
  const int m0 = blockIdx.y * 128, n0 = blockIdx.x * 128;
  const int wm = (w & 1) * 64, wn = (w >> 1) * 64;
  const int fr = lane & 15, quad = lane >> 4;

  f32x4 acca[4][4], accg[4][4];
  #pragma unroll
  for (int i = 0; i < 4; ++i)
    #pragma unroll
    for (int j = 0; j < 4; ++j)
      #pragma unroll
      for (int r = 0; r < 4; ++r){ acca[i][j][r] = 0.f; accg[i][j][r] = 0.f; }

  for (int k0 = 0; k0 < 512; k0 += 32){
    #pragma unroll
    for (int i = 0; i < 2; ++i){
      const int ch = tid + 256 * i;
      const int r = ch >> 2, c = ch & 3;
      *(uint4*)&As[r * LDST + c * 8] =
          *(const uint4*)(A + (size_t)(m0 + r) * 512 + k0 + c * 8);
      *(uint4*)&Ba[r * LDST + c * 8] =
          *(const uint4*)(B + (size_t)(n0 + r) * 512 + k0 + c * 8);
      *(uint4*)&Bg[r * LDST + c * 8] =
          *(const uint4*)(B + (size_t)(n0 + 2048 + r) * 512 + k0 + c * 8);
    }
    __syncthreads();
    bf16x8 af[4], ba[4], bg[4];
    #pragma unroll
    for (int i = 0; i < 4; ++i)
      af[i] = *(const bf16x8*)&As[(wm + i * 16 + fr) * LDST + quad * 8];
    #pragma unroll
    for (int j = 0; j < 4; ++j){
      ba[j] = *(const bf16x8*)&Ba[(wn + j * 16 + fr) * LDST + quad * 8];
      bg[j] = *(const bf16x8*)&Bg[(wn + j * 16 + fr) * LDST + quad * 8];
    }
    #pragma unroll
    for (int i = 0; i < 4; ++i)
      #pragma unroll
      for (int j = 0; j < 4; ++j){
        acca[i][j] = __builtin_amdgcn_mfma_f32_16x16x32_bf16(af[i], ba[j], acca[i][j], 0, 0, 0);
        accg[i][j] = __builtin_amdgcn_mfma_f32_16x16x32_bf16(af[i], bg[j], accg[i][j], 0, 0, 0);
      }
    __syncthreads();
  }

  #pragma unroll
  for (int i = 0; i < 4; ++i){
    #pragma unroll
    for (int r = 0; r < 4; ++r){
      const int cm = m0 + wm + i * 16 + quad * 4 + r;
      #pragma unroll
      for (int j = 0; j < 4; ++j){
        const int cn = n0 + wn + j * 16 + fr;
        const float a = acca[i][j][r] + b1[cn];
        const float g = accg[i][j][r] + b1[cn + 2048];
        const float ge = g * 0.5f * (1.0f + erff(g * 0.70710678118654752f));
        act[(size_t)cm * 2048 + cn] = f2bf(a * ge);
      }
    }
  }
}

// ---------------------------------------------------------------------------
// Row softmax over 2048 bf16 logits, in place.
// ---------------------------------------------------------------------------
__global__ __launch_bounds__(256) void softmax_kernel(bfu* __restrict__ sc){
  __shared__ float red[4];
  const int tid = threadIdx.x;
  const int lane = tid & 63, wv = tid >> 6;
  bfu* rp = sc + (size_t)blockIdx.x * NCTX;
  float x[8];
  #pragma unroll
  for (int j = 0; j < 8; ++j) x[j] = bf2f(rp[tid + (j << 8)]);
  float mx = x[0];
  #pragma unroll
  for (int j = 1; j < 8; ++j) mx = fmaxf(mx, x[j]);
  for (int o = 32; o; o >>= 1) mx = fmaxf(mx, __shfl_xor(mx, o, 64));
  if (lane == 0) red[wv] = mx;
  __syncthreads();
  mx = fmaxf(fmaxf(red[0], red[1]), fmaxf(red[2], red[3]));
  float sum = 0.f;
  #pragma unroll
  for (int j = 0; j < 8; ++j){ x[j] = __expf(x[j] - mx); sum += x[j]; }
  for (int o = 32; o; o >>= 1) sum += __shfl_xor(sum, o, 64);
  __syncthreads();
  if (lane == 0) red[wv] = sum;
  __syncthreads();
  sum = red[0] + red[1] + red[2] + red[3];
  const float inv = 1.0f / sum;
  #pragma unroll
  for (int j = 0; j < 8; ++j) rp[tid + (j << 8)] = f2bf(x[j] * inv);
}

// ---------------------------------------------------------------------------
// LayerNorm rows of 512 fp32 -> bf16.
// ---------------------------------------------------------------------------
__global__ __launch_bounds__(256) void ln_kernel(const float* __restrict__ in,
                                                 const float* __restrict__ g,
                                                 const float* __restrict__ b,
                                                 bfu* __restrict__ out){
  const int tid = threadIdx.x, lane = tid & 63, wv = tid >> 6;
  const size_t row = (size_t)blockIdx.x * 4 + wv;
  const float* rp = in + row * DIMV;
  float x[8];
  #pragma unroll
  for (int j = 0; j < 8; ++j) x[j] = rp[lane + (j << 6)];
  float s = 0.f;
  #pragma unroll
  for (int j = 0; j < 8; ++j) s += x[j];
  for (int o = 32; o; o >>= 1) s += __shfl_xor(s, o, 64);
  const float m = s * (1.0f / 512.0f);
  float s2 = 0.f;
  #pragma unroll
  for (int j = 0; j < 8; ++j){ const float d = x[j] - m; s2 = fmaf(d, d, s2); }
  for (int o = 32; o; o >>= 1) s2 += __shfl_xor(s2, o, 64);
  const float inv = 1.0f / sqrtf(s2 * (1.0f / 512.0f) + 1e-5f);
  bfu* op = out + row * DIMV;
  #pragma unroll
  for (int j = 0; j < 8; ++j){
    const int c = lane + (j << 6);
    op[c] = f2bf((x[j] - m) * inv * g[c] + b[c]);
  }
}

// ---------------------------------------------------------------------------
// Workspace (peak 117,473,280 B < proven 125.8 MB):
//   idx    @ 0          (32 KB)
//   emb_s  @ 32768      (25,165,824) \  act half (50,331,648) aliases
//   q_in   @ 25198592   (25,165,824) /  emb_s+q_in after wo GEMM
//   c_grp  @ 50364416   (8,388,608)  -> scores
//   k_grp  @ 58753024   (8,388,608)
//   v_grp  @ 67141632   (8,388,608)
//   vT     @ 75530240   (8,388,608)
//   qbuf   @ 83918848   (25,165,824) -> lnx
//   wT     @ 109084672  (8,388,608): wqT|wkvT|woT|w1T|w2T
// ---------------------------------------------------------------------------
extern "C" void kernel_launch(void* const* d_in, const int* in_sizes, int n_in,
                              void* d_out, int out_size, void* d_ws, size_t ws_size,
                              hipStream_t stream)
{
  (void)in_sizes; (void)n_in; (void)out_size;
  if (ws_size < 117473280ull) return;

  const float* pc    = (const float*)d_in[0];
  const float* pc2   = (const float*)d_in[1];
  const float* basis = (const float*)d_in[2];
  const float* pe_w  = (const float*)d_in[3];
  const float* pe_b  = (const float*)d_in[4];
  const float* lnq_g = (const float*)d_in[5];
  const float* lnq_b = (const float*)d_in[6];
  const float* lnc_g = (const float*)d_in[7];
  const float* lnc_b = (const float*)d_in[8];
  const float* wq    = (const float*)d_in[9];
  const float* wkv   = (const float*)d_in[10];
  const float* wo    = (const float*)d_in[11];
  const float* bo    = (const float*)d_in[12];
  const float* lnf_g = (const float*)d_in[13];
  const float* lnf_b = (const float*)d_in[14];
  const float* w1    = (const float*)d_in[15];
  const float* b1    = (const float*)d_in[16];
  const float* w2    = (const float*)d_in[17];
  const float* b2    = (const float*)d_in[18];
  float* xout = (float*)d_out;

  char* ws = (char*)d_ws;
  int* idxb   = (int*)(ws);
  bfu* emb_s  = (bfu*)(ws + 32768);
  bfu* q_in   = (bfu*)(ws + 25198592);
  bfu* c_grp  = (bfu*)(ws + 50364416);
  bfu* k_grp  = (bfu*)(ws + 58753024);
  bfu* v_grp  = (bfu*)(ws + 67141632);
  bfu* vT     = (bfu*)(ws + 75530240);
  bfu* qbuf   = (bfu*)(ws + 83918848);
  bfu* wqT    = (bfu*)(ws + 109084672);
  bfu* wkvT   = (bfu*)(ws + 109608960);
  bfu* woT    = (bfu*)(ws + 110657536);
  bfu* w1T    = (bfu*)(ws + 111181824);
  bfu* w2T    = (bfu*)(ws + 115376128);
  bfu* scores  = c_grp;
  bfu* attnout = q_in;
  bfu* lnx     = qbuf;
  bfu* actb    = emb_s;     // spans emb_s+q_in (one MLP half at a time)

  // 0. weight transposes (fp32 [K][N] -> bf16 [N][K])
  transp_kernel<float><<<dim3(16, 16, 1),  256, 0, stream>>>(wq,  wqT,  512,  512, 0, 0);
  transp_kernel<float><<<dim3(32, 16, 1),  256, 0, stream>>>(wkv, wkvT, 512, 1024, 0, 0);
  transp_kernel<float><<<dim3(16, 16, 1),  256, 0, stream>>>(wo,  woT,  512,  512, 0, 0);
  transp_kernel<float><<<dim3(128, 16, 1), 256, 0, stream>>>(w1,  w1T,  512, 4096, 0, 0);
  transp_kernel<float><<<dim3(16, 64, 1),  256, 0, stream>>>(w2,  w2T, 2048,  512, 0, 0);

  // 1. FPS (wave-synchronous, one wave per batch, register-resident)
  fps_kernel<<<NB, 64, 0, stream>>>(pc, idxb);

  // 2. latent embed -> emb_s (raw) + q_in (LN'd)
  embed_kernel<true, true><<<MROWS/16, 256, 0, stream>>>(
      pc, pc2, idxb, basis, pe_w, pe_b, lnq_g, lnq_b, emb_s, q_in, NLAT);

  // 3. q = q_in @ wq
  gemm_mfma<bfu, float, EPI_NONE><<<dim3(4, 192, 1), 256, 0, stream>>>(
      q_in, wqT, qbuf, nullptr, nullptr, nullptr, 1.0f,
      512, 512, 512, 512, 512, 0, 0, 0);

  // 4. per-group context pipeline
  for (int g = 0; g < NGRP; ++g){
    const int bt0 = g * GRP;
    embed_kernel<false, false><<<GROWS/16, 256, 0, stream>>>(
        pc + (size_t)bt0 * NCTX * 3, pc2 + (size_t)bt0 * NCTX * 3, nullptr,
        basis, pe_w, pe_b, lnc_g, lnc_b, nullptr, c_grp, NCTX);

    gemm_mfma<bfu, float, EPI_SPLIT><<<dim3(8, 64, 1), 256, 0, stream>>>(
        c_grp, wkvT, k_grp, v_grp, nullptr, nullptr, 1.0f,
        1024, 512, 512, 512, 512, 0, 0, 0);

    transp_kernel<bfu><<<dim3(16, 64, GRP), 256, 0, stream>>>(
        v_grp, vT, 2048, 512, 2048*512, 2048*512);

    // scores = (q @ k^T) * scale, bf16 (overwrites c_grp)
    gemm_mfma<bfu, float, EPI_SCALE><<<dim3(16, 4, GRP), 256, 0, stream>>>(
        qbuf + (size_t)bt0 * 262144, k_grp, scores, nullptr, nullptr, nullptr,
        0.044194173824159216f,
        2048, 512, 512, 512, 2048, 262144, 1048576, 1048576);

    softmax_kernel<<<GRP * 512, 256, 0, stream>>>(scores);

    // attnout = P @ V  (B = vT, [512][2048])
    gemm_mfma<bfu, float, EPI_NONE><<<dim3(4, 4, GRP), 256, 0, stream>>>(
        scores, vT, attnout + (size_t)bt0 * 262144, nullptr, nullptr, nullptr, 1.0f,
        512, 2048, 2048, 2048, 512, 1048576, 1048576, 262144);
  }

  // 5. x = attnout @ wo + bo + emb_s -> d_out (fp32)
  gemm_mfma<float, bfu, EPI_BIAS_RES><<<dim3(4, 192, 1), 256, 0, stream>>>(
      attnout, woT, xout, nullptr, bo, emb_s, 1.0f,
      512, 512, 512, 512, 512, 0, 0, 0);

  // 6. lnx = LN(x)
  ln_kernel<<<MROWS/4, 256, 0, stream>>>(xout, lnf_g, lnf_b, lnx);

  // 7/8. MLP in two row-halves (act buffer holds one half)
  for (int h = 0; h < 2; ++h){
    const size_t ro = (size_t)h * 12288;
    mlp1_mfma<<<dim3(16, 96, 1), 256, 0, stream>>>(
        lnx + ro * 512, w1T, b1, actb);
    gemm_mfma<float, float, EPI_BIAS_RES><<<dim3(4, 96, 1), 256, 0, stream>>>(
        actb, w2T, xout + ro * 512, nullptr, b2, xout + ro * 512, 1.0f,
        512, 2048, 2048, 2048, 512, 0, 0, 0);
  }
}

// Round 6
// 2527.076 us; speedup vs baseline: 1.0361x; 1.0361x over previous
//
#include <hip/hip_runtime.h>

// Problem constants
#define NB    16
#define NT    3
#define NCTX  2048
#define NLAT  512
#define DIMV  512
#define HALFD 256
#define NFEAT 51
#define NBT   48
#define MROWS 24576    // NBT*NLAT
#define GRP   4        // bt per context group
#define NGRP  12
#define GROWS 8192     // GRP*NCTX

typedef unsigned short bfu;   // bf16 storage as raw bits
typedef short bf16x8 __attribute__((ext_vector_type(8)));   // 8 bf16 = 4 VGPR
typedef float f32x4  __attribute__((ext_vector_type(4)));   // MFMA 16x16 acc
typedef float f32x2  __attribute__((ext_vector_type(2)));   // packed fp32 pair

__device__ __forceinline__ float bf2f(bfu u){ return __uint_as_float(((unsigned int)u) << 16); }
__device__ __forceinline__ bfu f2bf(float f){
  unsigned int u = __float_as_uint(f);
  u += 0x7FFFu + ((u >> 16) & 1u);          // RNE
  return (bfu)(u >> 16);
}
__device__ __forceinline__ float loadE(const float* p){ return *p; }
__device__ __forceinline__ float loadE(const bfu* p){ return bf2f(*p); }
__device__ __forceinline__ void storeE(float* p, float v){ *p = v; }
__device__ __forceinline__ void storeE(bfu* p, float v){ *p = f2bf(v); }
__device__ __forceinline__ bfu to_bfu(float f){ return f2bf(f); }
__device__ __forceinline__ bfu to_bfu(bfu u){ return u; }

// ---------------------------------------------------------------------------
// FPS, wave-synchronous. One 64-lane wave per batch.
// dist in 32 VGPRs (f32x2 pairs); coords in LDS packed for paired reads.
// Packed fp32 math with contraction OFF keeps numpy bit-exactness
// (((dx^2+dy^2)+dz^2), first-occurrence argmax).
// Wave argmax via DPP (row_shr 1/2/4/8 + row_bcast 15/31), result lane 63.
// Lexicographic (value, -index) max is associative -> exact first-occurrence.
// ---------------------------------------------------------------------------
#define DPP_ARGMAX_STAGE(CTRL)                                                \
  {                                                                           \
    const int svb = __builtin_amdgcn_update_dpp(vb, vb, CTRL, 0xF, 0xF, false); \
    const int sib = __builtin_amdgcn_update_dpp(ib, ib, CTRL, 0xF, 0xF, false); \
    const float sv = __int_as_float(svb);                                     \
    const float cv = __int_as_float(vb);                                      \
    if (sv > cv || (sv == cv && sib < ib)){ vb = svb; ib = sib; }             \
  }

__global__ __launch_bounds__(64) void fps_kernel(const float* __restrict__ pc,
                                                 int* __restrict__ idx_out){
#pragma clang fp contract(off)
  __shared__ float4 cxy4[1024];   // (x0,x1,y0,y1) for pair (i0, i0+64)
  __shared__ f32x2  cz2[1024];    // (z0,z1)
  const int b = blockIdx.x, lane = threadIdx.x;
  const float* src = pc + (size_t)b * (NT * NCTX * 3);

  f32x2 dist[16];
  #pragma unroll
  for (int p = 0; p < 16; ++p){
    const int i0 = lane + (p << 7);
    const int i1 = i0 + 64;
    const float x0 = src[i0*3+0], y0 = src[i0*3+1], z0 = src[i0*3+2];
    const float x1 = src[i1*3+0], y1 = src[i1*3+1], z1 = src[i1*3+2];
    cxy4[(p << 6) + lane] = make_float4(x0, x1, y0, y1);
    f32x2 z; z[0] = z0; z[1] = z1;
    cz2[(p << 6) + lane] = z;
    dist[p][0] = 1e10f; dist[p][1] = 1e10f;
  }
  if (lane == 0) idx_out[b * NLAT] = 0;
  __syncthreads();

  int last = 0;
  for (int step = 1; step < NLAT; ++step){
    // broadcast read of point `last` (wave-uniform address)
    const int lp = last >> 7, ll = last & 63, slot = (last >> 6) & 1;
    const float4 la = cxy4[(lp << 6) + ll];
    const f32x2  lc = cz2[(lp << 6) + ll];
    const float lx = slot ? la.y : la.x;
    const float ly = slot ? la.w : la.z;
    const float lz = slot ? lc[1] : lc[0];

    float bv[4] = {-1.f, -1.f, -1.f, -1.f};
    int   bi[4] = {0, 0, 0, 0};
    #pragma unroll
    for (int p = 0; p < 16; ++p){
      const int c = p & 3;                      // 4 independent chains
      const float4 a = cxy4[(p << 6) + lane];
      const f32x2  z = cz2[(p << 6) + lane];
      f32x2 dx; dx[0] = a.x - lx; dx[1] = a.y - lx;
      f32x2 dy; dy[0] = a.z - ly; dy[1] = a.w - ly;
      f32x2 dz; dz[0] = z[0] - lz; dz[1] = z[1] - lz;
      const f32x2 d = (dx*dx + dy*dy) + dz*dz;  // contract(off): exact numpy
      f32x2 nd;
      nd[0] = fminf(dist[p][0], d[0]);
      nd[1] = fminf(dist[p][1], d[1]);
      dist[p] = nd;
      const int i0 = lane + (p << 7);
      if (nd[0] > bv[c]){ bv[c] = nd[0]; bi[c] = i0; }      // ascending within chain
      if (nd[1] > bv[c]){ bv[c] = nd[1]; bi[c] = i0 + 64; }
    }
    // merge chains with index tie-break (chains interleave index ranges)
    if (bv[1] > bv[0] || (bv[1] == bv[0] && bi[1] < bi[0])){ bv[0] = bv[1]; bi[0] = bi[1]; }
    if (bv[3] > bv[2] || (bv[3] == bv[2] && bi[3] < bi[2])){ bv[2] = bv[3]; bi[2] = bi[3]; }
    if (bv[2] > bv[0] || (bv[2] == bv[0] && bi[2] < bi[0])){ bv[0] = bv[2]; bi[0] = bi[2]; }

    int vb = __float_as_int(bv[0]);
    int ib = bi[0];
    DPP_ARGMAX_STAGE(0x111)   // row_shr:1
    DPP_ARGMAX_STAGE(0x112)   // row_shr:2
    DPP_ARGMAX_STAGE(0x114)   // row_shr:4
    DPP_ARGMAX_STAGE(0x118)   // row_shr:8
    DPP_ARGMAX_STAGE(0x142)   // row_bcast:15
    DPP_ARGMAX_STAGE(0x143)   // row_bcast:31
    last = __builtin_amdgcn_readlane(ib, 63);   // full-wave argmax, uniform
    if (lane == 0) idx_out[b * NLAT + step] = last;
  }
}

// ---------------------------------------------------------------------------
// Fused (gather) + point_embed x2 + layernorm -> bf16. 16 points / block.
// ---------------------------------------------------------------------------
template<bool GATHER, bool WRITE_EMB>
__global__ __launch_bounds__(256) void embed_kernel(
    const float* __restrict__ pc, const float* __restrict__ pc2,
    const int* __restrict__ idx,
    const float* __restrict__ basis, const float* __restrict__ pe_w,
    const float* __restrict__ pe_b,
    const float* __restrict__ ln_g, const float* __restrict__ ln_b,
    bfu* __restrict__ emb, bfu* __restrict__ lnout, int nppbt)
{
  __shared__ float feat[2][16][NFEAT + 1];
  __shared__ float outb[16][DIMV];
  const int tid = threadIdx.x;
  const int p0 = blockIdx.x << 4;

  if (tid < 32){
    const int s = tid >> 4, p = tid & 15;
    const int gp = p0 + p;
    const int bt = gp / nppbt;
    const int n  = gp - bt * nppbt;
    const int bb = bt / NT;
    const int srcn = GATHER ? idx[bb * NLAT + n] : n;
    const float* sp = (s ? pc2 : pc) + ((size_t)bt * NCTX + srcn) * 3;
    const float x0 = sp[0], x1 = sp[1], x2 = sp[2];
    #pragma unroll
    for (int e = 0; e < 24; ++e){
      const float pr = __fadd_rn(__fadd_rn(__fmul_rn(x0, basis[e]),
                                           __fmul_rn(x1, basis[24 + e])),
                                 __fmul_rn(x2, basis[48 + e]));
      feat[s][p][e]      = sinf(pr);
      feat[s][p][24 + e] = cosf(pr);
    }
    feat[s][p][48] = x0; feat[s][p][49] = x1; feat[s][p][50] = x2;
  }
  __syncthreads();

  {
    float w[NFEAT];
    #pragma unroll
    for (int k = 0; k < NFEAT; ++k) w[k] = pe_w[k * HALFD + tid];
    const float bv = pe_b[tid];
    #pragma unroll
    for (int half = 0; half < 2; ++half){
      for (int p = 0; p < 16; ++p){
        float acc = bv;
        #pragma unroll
        for (int k = 0; k < NFEAT; ++k) acc = fmaf(feat[half][p][k], w[k], acc);
        outb[p][half * HALFD + tid] = acc;
      }
    }
  }
  __syncthreads();

  const int lane = tid & 63, wv = tid >> 6;
  for (int pp = 0; pp < 4; ++pp){
    const int p = (wv << 2) + pp;
    const size_t gp = (size_t)p0 + p;
    float x[8];
    #pragma unroll
    for (int j = 0; j < 8; ++j) x[j] = outb[p][lane + (j << 6)];
    float s = 0.f;
    #pragma unroll
    for (int j = 0; j < 8; ++j) s += x[j];
    for (int o = 32; o; o >>= 1) s += __shfl_xor(s, o, 64);
    const float m = s * (1.0f / 512.0f);
    float s2 = 0.f;
    #pragma unroll
    for (int j = 0; j < 8; ++j){ const float d = x[j] - m; s2 = fmaf(d, d, s2); }
    for (int o = 32; o; o >>= 1) s2 += __shfl_xor(s2, o, 64);
    const float inv = 1.0f / sqrtf(s2 * (1.0f / 512.0f) + 1e-5f);
    #pragma unroll
    for (int j = 0; j < 8; ++j){
      const int c = lane + (j << 6);
      const float r = (x[j] - m) * inv * ln_g[c] + ln_b[c];
      const size_t o2 = gp * DIMV + c;
      if (WRITE_EMB) emb[o2] = f2bf(x[j]);
      lnout[o2] = f2bf(r);
    }
  }
}

// ---------------------------------------------------------------------------
// Tiled transpose: in [R][C] (fp32 or bf16) -> out bf16 [C][R]. 32x32 tiles.
// ---------------------------------------------------------------------------
template<typename TIN>
__global__ __launch_bounds__(256) void transp_kernel(
    const TIN* __restrict__ in, bfu* __restrict__ out, int R, int C,
    long long sIn, long long sOut)
{
  __shared__ bfu t[32][33];
  in  += (size_t)blockIdx.z * sIn;
  out += (size_t)blockIdx.z * sOut;
  const int c0 = blockIdx.x * 32, r0 = blockIdx.y * 32;
  const int tx = threadIdx.x & 31, ty = threadIdx.x >> 5;
  #pragma unroll
  for (int rr = ty; rr < 32; rr += 8)
    t[rr][tx] = to_bfu(in[(size_t)(r0 + rr) * C + c0 + tx]);
  __syncthreads();
  #pragma unroll
  for (int rr = ty; rr < 32; rr += 8)
    out[(size_t)(c0 + rr) * R + r0 + tx] = t[tx][rr];
}

// ---------------------------------------------------------------------------
// MFMA GEMM: C[M][N] = A[M][K] * B[N][K]^T, all bf16 inputs.
// 128x128 block tile, 4 waves (2x2), each wave 64x64 = 4x4 MFMA 16x16x32.
// LDS rows padded to 40 shorts (80 B = 20 banks -> 2-way max conflicts).
// ---------------------------------------------------------------------------
#define EPI_NONE     0
#define EPI_SPLIT    1
#define EPI_SCALE    2
#define EPI_BIAS_RES 3
#define LDST 40

template<typename TC, typename TR, int EPI>
__global__ __launch_bounds__(256, 2) void gemm_mfma(
    const bfu* __restrict__ A, const bfu* __restrict__ B,
    TC* __restrict__ C, TC* __restrict__ C2,
    const float* __restrict__ bias, const TR* __restrict__ res,
    float scale, int N, int K, int lda, int ldb, int ldc,
    long long sA, long long sB, long long sC)
{
  const int bz = blockIdx.z;
  A += (size_t)bz * sA;
  B += (size_t)bz * sB;
  const size_t coff = (size_t)bz * sC;

  __shared__ __align__(16) short As[128 * LDST];
  __shared__ __align__(16) short Bs[128 * LDST];

  const int tid = threadIdx.x;
  const int lane = tid & 63, w = tid >> 6;
  const int m0 = blockIdx.y * 128, n0 = blockIdx.x * 128;
  const int wm = (w & 1) * 64, wn = (w >> 1) * 64;
  const int fr = lane & 15, quad = lane >> 4;

  f32x4 acc[4][4];
  #pragma unroll
  for (int i = 0; i < 4; ++i)
    #pragma unroll
    for (int j = 0; j < 4; ++j)
      #pragma unroll
      for (int r = 0; r < 4; ++r) acc[i][j][r] = 0.f;

  for (int k0 = 0; k0 < K; k0 += 32){
    #pragma unroll
    for (int i = 0; i < 2; ++i){
      const int ch = tid + 256 * i;             // 512 16B-chunks per tile
      const int r = ch >> 2, c = ch & 3;
      *(uint4*)&As[r * LDST + c * 8] =
          *(const uint4*)(A + (size_t)(m0 + r) * lda + k0 + c * 8);
      *(uint4*)&Bs[r * LDST + c * 8] =
          *(const uint4*)(B + (size_t)(n0 + r) * ldb + k0 + c * 8);
    }
    __syncthreads();
    bf16x8 af[4], bf[4];
    #pragma unroll
    for (int i = 0; i < 4; ++i)
      af[i] = *(const bf16x8*)&As[(wm + i * 16 + fr) * LDST + quad * 8];
    #pragma unroll
    for (int j = 0; j < 4; ++j)
      bf[j] = *(const bf16x8*)&Bs[(wn + j * 16 + fr) * LDST + quad * 8];
    #pragma unroll
    for (int i = 0; i < 4; ++i)
      #pragma unroll
      for (int j = 0; j < 4; ++j)
        acc[i][j] = __builtin_amdgcn_mfma_f32_16x16x32_bf16(af[i], bf[j], acc[i][j], 0, 0, 0);
    __syncthreads();
  }

  // C/D layout: col = lane&15, row = quad*4 + reg
  TC* Cp = C + coff;
  #pragma unroll
  for (int i = 0; i < 4; ++i){
    #pragma unroll
    for (int r = 0; r < 4; ++r){
      const int cm = m0 + wm + i * 16 + quad * 4 + r;
      #pragma unroll
      for (int j = 0; j < 4; ++j){
        const int cn = n0 + wn + j * 16 + fr;
        float v = acc[i][j][r];
        if (EPI == EPI_SCALE)    v *= scale;
        if (EPI == EPI_BIAS_RES) v = v + bias[cn] + loadE(&res[coff + (size_t)cm * ldc + cn]);
        if (EPI == EPI_SPLIT){
          const int half = N >> 1;
          if (cn < half) storeE(&C [(size_t)cm * half + cn],          v);
          else           storeE(&C2[(size_t)cm * half + (cn - half)], v);
        } else {
          storeE(&Cp[(size_t)cm * ldc + cn], v);
        }
      }
    }
  }
}

// ---------------------------------------------------------------------------
// Fused MLP1 + exact GeLU (MFMA): act = (A@w1T[a]+b1a) * gelu(A@w1T[g]+b1g).
// ---------------------------------------------------------------------------
__global__ __launch_bounds__(256, 1) void mlp1_mfma(
    const bfu* __restrict__ A, const bfu* __restrict__ B,  // B = w1T [4096][512]
    const float* __restrict__ b1, bfu* __restrict__ act)
{
  __shared__ __align__(16) short As[128 * LDST];
  __shared__ __align__(16) short Ba[128 * LDST];
  __shared__ __align__(16) short Bg[128 * LDST];

  const int tid = threadIdx.x;
  const int lane = tid & 63, w = tid >> 6;
  const int m0 = blockIdx.y * 128, n0 = blockIdx.x * 128;
  const int wm = (w & 1) * 64, wn = (w >> 1) * 64;
  const int fr = lane & 15, quad = lane >> 4;

  f32x4 acca[4][4], accg[4][4];
  #pragma unroll
  for (int i = 0; i < 4; ++i)
    #pragma unroll
    for (int j = 0; j < 4; ++j)
      #pragma unroll
      for (int r = 0; r < 4; ++r){ acca[i][j][r] = 0.f; accg[i][j][r] = 0.f; }

  for (int k0 = 0; k0 < 512; k0 += 32){
    #pragma unroll
    for (int i = 0; i < 2; ++i){
      const int ch = tid + 256 * i;
      const int r = ch >> 2, c = ch & 3;
      *(uint4*)&As[r * LDST + c * 8] =
          *(const uint4*)(A + (size_t)(m0 + r) * 512 + k0 + c * 8);
      *(uint4*)&Ba[r * LDST + c * 8] =
          *(const uint4*)(B + (size_t)(n0 + r) * 512 + k0 + c * 8);
      *(uint4*)&Bg[r * LDST + c * 8] =
          *(const uint4*)(B + (size_t)(n0 + 2048 + r) * 512 + k0 + c * 8);
    }
    __syncthreads();
    bf16x8 af[4], ba[4], bg[4];
    #pragma unroll
    for (int i = 0; i < 4; ++i)
      af[i] = *(const bf16x8*)&As[(wm + i * 16 + fr) * LDST + quad * 8];
    #pragma unroll
    for (int j = 0; j < 4; ++j){
      ba[j] = *(const bf16x8*)&Ba[(wn + j * 16 + fr) * LDST + quad * 8];
      bg[j] = *(const bf16x8*)&Bg[(wn + j * 16 + fr) * LDST + quad * 8];
    }
    #pragma unroll
    for (int i = 0; i < 4; ++i)
      #pragma unroll
      for (int j = 0; j < 4; ++j){
        acca[i][j] = __builtin_amdgcn_mfma_f32_16x16x32_bf16(af[i], ba[j], acca[i][j], 0, 0, 0);
        accg[i][j] = __builtin_amdgcn_mfma_f32_16x16x32_bf16(af[i], bg[j], accg[i][j], 0, 0, 0);
      }
    __syncthreads();
  }

  #pragma unroll
  for (int i = 0; i < 4; ++i){
    #pragma unroll
    for (int r = 0; r < 4; ++r){
      const int cm = m0 + wm + i * 16 + quad * 4 + r;
      #pragma unroll
      for (int j = 0; j < 4; ++j){
        const int cn = n0 + wn + j * 16 + fr;
        const float a = acca[i][j][r] + b1[cn];
        const float g = accg[i][j][r] + b1[cn + 2048];
        const float ge = g * 0.5f * (1.0f + erff(g * 0.70710678118654752f));
        act[(size_t)cm * 2048 + cn] = f2bf(a * ge);
      }
    }
  }
}

// ---------------------------------------------------------------------------
// Row softmax over 2048 bf16 logits, in place.
// ---------------------------------------------------------------------------
__global__ __launch_bounds__(256) void softmax_kernel(bfu* __restrict__ sc){
  __shared__ float red[4];
  const int tid = threadIdx.x;
  const int lane = tid & 63, wv = tid >> 6;
  bfu* rp = sc + (size_t)blockIdx.x * NCTX;
  float x[8];
  #pragma unroll
  for (int j = 0; j < 8; ++j) x[j] = bf2f(rp[tid + (j << 8)]);
  float mx = x[0];
  #pragma unroll
  for (int j = 1; j < 8; ++j) mx = fmaxf(mx, x[j]);
  for (int o = 32; o; o >>= 1) mx = fmaxf(mx, __shfl_xor(mx, o, 64));
  if (lane == 0) red[wv] = mx;
  __syncthreads();
  mx = fmaxf(fmaxf(red[0], red[1]), fmaxf(red[2], red[3]));
  float sum = 0.f;
  #pragma unroll
  for (int j = 0; j < 8; ++j){ x[j] = __expf(x[j] - mx); sum += x[j]; }
  for (int o = 32; o; o >>= 1) sum += __shfl_xor(sum, o, 64);
  __syncthreads();
  if (lane == 0) red[wv] = sum;
  __syncthreads();
  sum = red[0] + red[1] + red[2] + red[3];
  const float inv = 1.0f / sum;
  #pragma unroll
  for (int j = 0; j < 8; ++j) rp[tid + (j << 8)] = f2bf(x[j] * inv);
}

// ---------------------------------------------------------------------------
// LayerNorm rows of 512 fp32 -> bf16.
// ---------------------------------------------------------------------------
__global__ __launch_bounds__(256) void ln_kernel(const float* __restrict__ in,
                                                 const float* __restrict__ g,
                                                 const float* __restrict__ b,
                                                 bfu* __restrict__ out){
  const int tid = threadIdx.x, lane = tid & 63, wv = tid >> 6;
  const size_t row = (size_t)blockIdx.x * 4 + wv;
  const float* rp = in + row * DIMV;
  float x[8];
  #pragma unroll
  for (int j = 0; j < 8; ++j) x[j] = rp[lane + (j << 6)];
  float s = 0.f;
  #pragma unroll
  for (int j = 0; j < 8; ++j) s += x[j];
  for (int o = 32; o; o >>= 1) s += __shfl_xor(s, o, 64);
  const float m = s * (1.0f / 512.0f);
  float s2 = 0.f;
  #pragma unroll
  for (int j = 0; j < 8; ++j){ const float d = x[j] - m; s2 = fmaf(d, d, s2); }
  for (int o = 32; o; o >>= 1) s2 += __shfl_xor(s2, o, 64);
  const float inv = 1.0f / sqrtf(s2 * (1.0f / 512.0f) + 1e-5f);
  bfu* op = out + row * DIMV;
  #pragma unroll
  for (int j = 0; j < 8; ++j){
    const int c = lane + (j << 6);
    op[c] = f2bf((x[j] - m) * inv * g[c] + b[c]);
  }
}

// ---------------------------------------------------------------------------
// Workspace (peak 117,473,280 B < proven 125.8 MB):
//   idx    @ 0          (32 KB)
//   emb_s  @ 32768      (25,165,824) \  act half (50,331,648) aliases
//   q_in   @ 25198592   (25,165,824) /  emb_s+q_in after wo GEMM
//   c_grp  @ 50364416   (8,388,608)  -> scores
//   k_grp  @ 58753024   (8,388,608)
//   v_grp  @ 67141632   (8,388,608)
//   vT     @ 75530240   (8,388,608)
//   qbuf   @ 83918848   (25,165,824) -> lnx
//   wT     @ 109084672  (8,388,608): wqT|wkvT|woT|w1T|w2T
// ---------------------------------------------------------------------------
extern "C" void kernel_launch(void* const* d_in, const int* in_sizes, int n_in,
                              void* d_out, int out_size, void* d_ws, size_t ws_size,
                              hipStream_t stream)
{
  (void)in_sizes; (void)n_in; (void)out_size;
  if (ws_size < 117473280ull) return;

  const float* pc    = (const float*)d_in[0];
  const float* pc2   = (const float*)d_in[1];
  const float* basis = (const float*)d_in[2];
  const float* pe_w  = (const float*)d_in[3];
  const float* pe_b  = (const float*)d_in[4];
  const float* lnq_g = (const float*)d_in[5];
  const float* lnq_b = (const float*)d_in[6];
  const float* lnc_g = (const float*)d_in[7];
  const float* lnc_b = (const float*)d_in[8];
  const float* wq    = (const float*)d_in[9];
  const float* wkv   = (const float*)d_in[10];
  const float* wo    = (const float*)d_in[11];
  const float* bo    = (const float*)d_in[12];
  const float* lnf_g = (const float*)d_in[13];
  const float* lnf_b = (const float*)d_in[14];
  const float* w1    = (const float*)d_in[15];
  const float* b1    = (const float*)d_in[16];
  const float* w2    = (const float*)d_in[17];
  const float* b2    = (const float*)d_in[18];
  float* xout = (float*)d_out;

  char* ws = (char*)d_ws;
  int* idxb   = (int*)(ws);
  bfu* emb_s  = (bfu*)(ws + 32768);
  bfu* q_in   = (bfu*)(ws + 25198592);
  bfu* c_grp  = (bfu*)(ws + 50364416);
  bfu* k_grp  = (bfu*)(ws + 58753024);
  bfu* v_grp  = (bfu*)(ws + 67141632);
  bfu* vT     = (bfu*)(ws + 75530240);
  bfu* qbuf   = (bfu*)(ws + 83918848);
  bfu* wqT    = (bfu*)(ws + 109084672);
  bfu* wkvT   = (bfu*)(ws + 109608960);
  bfu* woT    = (bfu*)(ws + 110657536);
  bfu* w1T    = (bfu*)(ws + 111181824);
  bfu* w2T    = (bfu*)(ws + 115376128);
  bfu* scores  = c_grp;
  bfu* attnout = q_in;
  bfu* lnx     = qbuf;
  bfu* actb    = emb_s;     // spans emb_s+q_in (one MLP half at a time)

  // 0. weight transposes (fp32 [K][N] -> bf16 [N][K])
  transp_kernel<float><<<dim3(16, 16, 1),  256, 0, stream>>>(wq,  wqT,  512,  512, 0, 0);
  transp_kernel<float><<<dim3(32, 16, 1),  256, 0, stream>>>(wkv, wkvT, 512, 1024, 0, 0);
  transp_kernel<float><<<dim3(16, 16, 1),  256, 0, stream>>>(wo,  woT,  512,  512, 0, 0);
  transp_kernel<float><<<dim3(128, 16, 1), 256, 0, stream>>>(w1,  w1T,  512, 4096, 0, 0);
  transp_kernel<float><<<dim3(16, 64, 1),  256, 0, stream>>>(w2,  w2T, 2048,  512, 0, 0);

  // 1. FPS (wave-synchronous, one wave per batch, DPP argmax)
  fps_kernel<<<NB, 64, 0, stream>>>(pc, idxb);

  // 2. latent embed -> emb_s (raw) + q_in (LN'd)
  embed_kernel<true, true><<<MROWS/16, 256, 0, stream>>>(
      pc, pc2, idxb, basis, pe_w, pe_b, lnq_g, lnq_b, emb_s, q_in, NLAT);

  // 3. q = q_in @ wq
  gemm_mfma<bfu, float, EPI_NONE><<<dim3(4, 192, 1), 256, 0, stream>>>(
      q_in, wqT, qbuf, nullptr, nullptr, nullptr, 1.0f,
      512, 512, 512, 512, 512, 0, 0, 0);

  // 4. per-group context pipeline
  for (int g = 0; g < NGRP; ++g){
    const int bt0 = g * GRP;
    embed_kernel<false, false><<<GROWS/16, 256, 0, stream>>>(
        pc + (size_t)bt0 * NCTX * 3, pc2 + (size_t)bt0 * NCTX * 3, nullptr,
        basis, pe_w, pe_b, lnc_g, lnc_b, nullptr, c_grp, NCTX);

    gemm_mfma<bfu, float, EPI_SPLIT><<<dim3(8, 64, 1), 256, 0, stream>>>(
        c_grp, wkvT, k_grp, v_grp, nullptr, nullptr, 1.0f,
        1024, 512, 512, 512, 512, 0, 0, 0);

    transp_kernel<bfu><<<dim3(16, 64, GRP), 256, 0, stream>>>(
        v_grp, vT, 2048, 512, 2048*512, 2048*512);

    // scores = (q @ k^T) * scale, bf16 (overwrites c_grp)
    gemm_mfma<bfu, float, EPI_SCALE><<<dim3(16, 4, GRP), 256, 0, stream>>>(
        qbuf + (size_t)bt0 * 262144, k_grp, scores, nullptr, nullptr, nullptr,
        0.044194173824159216f,
        2048, 512, 512, 512, 2048, 262144, 1048576, 1048576);

    softmax_kernel<<<GRP * 512, 256, 0, stream>>>(scores);

    // attnout = P @ V  (B = vT, [512][2048])
    gemm_mfma<bfu, float, EPI_NONE><<<dim3(4, 4, GRP), 256, 0, stream>>>(
        scores, vT, attnout + (size_t)bt0 * 262144, nullptr, nullptr, nullptr, 1.0f,
        512, 2048, 2048, 2048, 512, 1048576, 1048576, 262144);
  }

  // 5. x = attnout @ wo + bo + emb_s -> d_out (fp32)
  gemm_mfma<float, bfu, EPI_BIAS_RES><<<dim3(4, 192, 1), 256, 0, stream>>>(
      attnout, woT, xout, nullptr, bo, emb_s, 1.0f,
      512, 512, 512, 512, 512, 0, 0, 0);

  // 6. lnx = LN(x)
  ln_kernel<<<MROWS/4, 256, 0, stream>>>(xout, lnf_g, lnf_b, lnx);

  // 7/8. MLP in two row-halves (act buffer holds one half)
  for (int h = 0; h < 2; ++h){
    const size_t ro = (size_t)h * 12288;
    mlp1_mfma<<<dim3(16, 96, 1), 256, 0, stream>>>(
        lnx + ro * 512, w1T, b1, actb);
    gemm_mfma<float, float, EPI_BIAS_RES><<<dim3(4, 96, 1), 256, 0, stream>>>(
        actb, w2T, xout + ro * 512, nullptr, b2, xout + ro * 512, 1.0f,
        512, 2048, 2048, 2048, 512, 0, 0, 0);
  }
}

// Round 7
// 2495.088 us; speedup vs baseline: 1.0494x; 1.0128x over previous
//
#include <hip/hip_runtime.h>

// Problem constants
#define NB    16
#define NT    3
#define NCTX  2048
#define NLAT  512
#define DIMV  512
#define HALFD 256
#define NFEAT 51
#define NBT   48
#define MROWS 24576    // NBT*NLAT
#define GRP   4        // bt per context group
#define NGRP  12
#define GROWS 8192     // GRP*NCTX

typedef unsigned short bfu;   // bf16 storage as raw bits
typedef short bf16x8 __attribute__((ext_vector_type(8)));   // 8 bf16 = 4 VGPR
typedef float f32x4  __attribute__((ext_vector_type(4)));   // MFMA 16x16 acc
typedef float f32x2  __attribute__((ext_vector_type(2)));   // packed fp32 pair

__device__ __forceinline__ float bf2f(bfu u){ return __uint_as_float(((unsigned int)u) << 16); }
__device__ __forceinline__ bfu f2bf(float f){
  unsigned int u = __float_as_uint(f);
  u += 0x7FFFu + ((u >> 16) & 1u);          // RNE
  return (bfu)(u >> 16);
}
__device__ __forceinline__ float loadE(const float* p){ return *p; }
__device__ __forceinline__ float loadE(const bfu* p){ return bf2f(*p); }
__device__ __forceinline__ void storeE(float* p, float v){ *p = v; }
__device__ __forceinline__ void storeE(bfu* p, float v){ *p = f2bf(v); }
__device__ __forceinline__ bfu to_bfu(float f){ return f2bf(f); }
__device__ __forceinline__ bfu to_bfu(bfu u){ return u; }

// ---------------------------------------------------------------------------
// FPS: 4 waves per batch (256 thr), 8 pts/lane. dist in 8 VGPRs; coords in
// LDS packed pair-wise. Per step: per-lane scan -> in-wave DPP argmax
// (row_shr 1/2/4/8 + row_bcast 15/31, result lane 63; HW-verified R6) ->
// lane63 posts (v,i) to parity-double-buffered LDS -> ONE barrier -> all
// threads merge 4 pairs (disjoint-ascending wave ranges + idx tie-break
// preserve first-occurrence). Packed fp32 with contract(off): bit-exact
// numpy (((dx^2+dy^2)+dz^2), fminf, strict-> ascending scan).
// ---------------------------------------------------------------------------
#define DPP_ARGMAX_STAGE(CTRL)                                                \
  {                                                                           \
    const int svb = __builtin_amdgcn_update_dpp(vb, vb, CTRL, 0xF, 0xF, false); \
    const int sib = __builtin_amdgcn_update_dpp(ib, ib, CTRL, 0xF, 0xF, false); \
    const float sv = __int_as_float(svb);                                     \
    const float cv = __int_as_float(vb);                                      \
    if (sv > cv || (sv == cv && sib < ib)){ vb = svb; ib = sib; }             \
  }

__global__ __launch_bounds__(256) void fps_kernel(const float* __restrict__ pc,
                                                  int* __restrict__ idx_out){
#pragma clang fp contract(off)
  __shared__ float4 cxy4[1024];   // (x0,x1,y0,y1) for pair (i0, i0+64)
  __shared__ f32x2  cz2[1024];    // (z0,z1)
  __shared__ float  mval[2][4];
  __shared__ int    midx[2][4];
  const int b = blockIdx.x, tid = threadIdx.x;
  const int lane = tid & 63, w = tid >> 6;
  const int base = w << 9;                        // wave owns [512w, 512w+512)
  const float* src = pc + (size_t)b * (NT * NCTX * 3);

  f32x2 dist[4];
  #pragma unroll
  for (int p = 0; p < 4; ++p){
    const int i0 = base + (p << 7) + lane;
    const int i1 = i0 + 64;
    const float x0 = src[i0*3+0], y0 = src[i0*3+1], z0 = src[i0*3+2];
    const float x1 = src[i1*3+0], y1 = src[i1*3+1], z1 = src[i1*3+2];
    cxy4[(w << 8) + (p << 6) + lane] = make_float4(x0, x1, y0, y1);
    f32x2 z; z[0] = z0; z[1] = z1;
    cz2[(w << 8) + (p << 6) + lane] = z;
    dist[p][0] = 1e10f; dist[p][1] = 1e10f;
  }
  if (tid == 0) idx_out[b * NLAT] = 0;
  __syncthreads();

  int last = 0;
  for (int step = 1; step < NLAT; ++step){
    // broadcast read of point `last` (wave-uniform address)
    const int lw = last >> 9, lo = last & 511;
    const int li = (lw << 8) + ((lo >> 7) << 6) + (lo & 63);
    const int slot = (lo >> 6) & 1;
    const float4 la = cxy4[li];
    const f32x2  lc = cz2[li];
    const float lx = slot ? la.y : la.x;
    const float ly = slot ? la.w : la.z;
    const float lz = slot ? lc[1] : lc[0];

    float bv[2] = {-1.f, -1.f};
    int   bi[2] = {0, 0};
    #pragma unroll
    for (int p = 0; p < 4; ++p){
      const int c = p & 1;                        // 2 independent chains
      const float4 a = cxy4[(w << 8) + (p << 6) + lane];
      const f32x2  z = cz2[(w << 8) + (p << 6) + lane];
      f32x2 dx; dx[0] = a.x - lx; dx[1] = a.y - lx;
      f32x2 dy; dy[0] = a.z - ly; dy[1] = a.w - ly;
      f32x2 dz; dz[0] = z[0] - lz; dz[1] = z[1] - lz;
      const f32x2 d = (dx*dx + dy*dy) + dz*dz;    // contract(off): exact numpy
      f32x2 nd;
      nd[0] = fminf(dist[p][0], d[0]);
      nd[1] = fminf(dist[p][1], d[1]);
      dist[p] = nd;
      const int i0 = base + (p << 7) + lane;
      if (nd[0] > bv[c]){ bv[c] = nd[0]; bi[c] = i0; }      // ascending in chain
      if (nd[1] > bv[c]){ bv[c] = nd[1]; bi[c] = i0 + 64; }
    }
    if (bv[1] > bv[0] || (bv[1] == bv[0] && bi[1] < bi[0])){ bv[0] = bv[1]; bi[0] = bi[1]; }

    int vb = __float_as_int(bv[0]);
    int ib = bi[0];
    DPP_ARGMAX_STAGE(0x111)   // row_shr:1
    DPP_ARGMAX_STAGE(0x112)   // row_shr:2
    DPP_ARGMAX_STAGE(0x114)   // row_shr:4
    DPP_ARGMAX_STAGE(0x118)   // row_shr:8
    DPP_ARGMAX_STAGE(0x142)   // row_bcast:15
    DPP_ARGMAX_STAGE(0x143)   // row_bcast:31

    const int par = step & 1;                     // double-buffer: no WAR barrier
    if (lane == 63){ mval[par][w] = __int_as_float(vb); midx[par][w] = ib; }
    __syncthreads();
    float fv = mval[par][0]; int fi = midx[par][0];
    #pragma unroll
    for (int q = 1; q < 4; ++q){
      const float qv = mval[par][q]; const int qi = midx[par][q];
      if (qv > fv || (qv == fv && qi < fi)){ fv = qv; fi = qi; }
    }
    last = fi;                                    // all threads agree
    if (tid == 0) idx_out[b * NLAT + step] = fi;
  }
}

// ---------------------------------------------------------------------------
// Fused (gather) + point_embed x2 + layernorm -> bf16. 16 points / block.
// ---------------------------------------------------------------------------
template<bool GATHER, bool WRITE_EMB>
__global__ __launch_bounds__(256) void embed_kernel(
    const float* __restrict__ pc, const float* __restrict__ pc2,
    const int* __restrict__ idx,
    const float* __restrict__ basis, const float* __restrict__ pe_w,
    const float* __restrict__ pe_b,
    const float* __restrict__ ln_g, const float* __restrict__ ln_b,
    bfu* __restrict__ emb, bfu* __restrict__ lnout, int nppbt)
{
  __shared__ float feat[2][16][NFEAT + 1];
  __shared__ float outb[16][DIMV];
  const int tid = threadIdx.x;
  const int p0 = blockIdx.x << 4;

  if (tid < 32){
    const int s = tid >> 4, p = tid & 15;
    const int gp = p0 + p;
    const int bt = gp / nppbt;
    const int n  = gp - bt * nppbt;
    const int bb = bt / NT;
    const int srcn = GATHER ? idx[bb * NLAT + n] : n;
    const float* sp = (s ? pc2 : pc) + ((size_t)bt * NCTX + srcn) * 3;
    const float x0 = sp[0], x1 = sp[1], x2 = sp[2];
    #pragma unroll
    for (int e = 0; e < 24; ++e){
      const float pr = __fadd_rn(__fadd_rn(__fmul_rn(x0, basis[e]),
                                           __fmul_rn(x1, basis[24 + e])),
                                 __fmul_rn(x2, basis[48 + e]));
      feat[s][p][e]      = sinf(pr);
      feat[s][p][24 + e] = cosf(pr);
    }
    feat[s][p][48] = x0; feat[s][p][49] = x1; feat[s][p][50] = x2;
  }
  __syncthreads();

  {
    float w[NFEAT];
    #pragma unroll
    for (int k = 0; k < NFEAT; ++k) w[k] = pe_w[k * HALFD + tid];
    const float bv = pe_b[tid];
    #pragma unroll
    for (int half = 0; half < 2; ++half){
      for (int p = 0; p < 16; ++p){
        float acc = bv;
        #pragma unroll
        for (int k = 0; k < NFEAT; ++k) acc = fmaf(feat[half][p][k], w[k], acc);
        outb[p][half * HALFD + tid] = acc;
      }
    }
  }
  __syncthreads();

  const int lane = tid & 63, wv = tid >> 6;
  for (int pp = 0; pp < 4; ++pp){
    const int p = (wv << 2) + pp;
    const size_t gp = (size_t)p0 + p;
    float x[8];
    #pragma unroll
    for (int j = 0; j < 8; ++j) x[j] = outb[p][lane + (j << 6)];
    float s = 0.f;
    #pragma unroll
    for (int j = 0; j < 8; ++j) s += x[j];
    for (int o = 32; o; o >>= 1) s += __shfl_xor(s, o, 64);
    const float m = s * (1.0f / 512.0f);
    float s2 = 0.f;
    #pragma unroll
    for (int j = 0; j < 8; ++j){ const float d = x[j] - m; s2 = fmaf(d, d, s2); }
    for (int o = 32; o; o >>= 1) s2 += __shfl_xor(s2, o, 64);
    const float inv = 1.0f / sqrtf(s2 * (1.0f / 512.0f) + 1e-5f);
    #pragma unroll
    for (int j = 0; j < 8; ++j){
      const int c = lane + (j << 6);
      const float r = (x[j] - m) * inv * ln_g[c] + ln_b[c];
      const size_t o2 = gp * DIMV + c;
      if (WRITE_EMB) emb[o2] = f2bf(x[j]);
      lnout[o2] = f2bf(r);
    }
  }
}

// ---------------------------------------------------------------------------
// Tiled transpose: in [R][C] (fp32 or bf16) -> out bf16 [C][R]. 32x32 tiles.
// ---------------------------------------------------------------------------
template<typename TIN>
__global__ __launch_bounds__(256) void transp_kernel(
    const TIN* __restrict__ in, bfu* __restrict__ out, int R, int C,
    long long sIn, long long sOut)
{
  __shared__ bfu t[32][33];
  in  += (size_t)blockIdx.z * sIn;
  out += (size_t)blockIdx.z * sOut;
  const int c0 = blockIdx.x * 32, r0 = blockIdx.y * 32;
  const int tx = threadIdx.x & 31, ty = threadIdx.x >> 5;
  #pragma unroll
  for (int rr = ty; rr < 32; rr += 8)
    t[rr][tx] = to_bfu(in[(size_t)(r0 + rr) * C + c0 + tx]);
  __syncthreads();
  #pragma unroll
  for (int rr = ty; rr < 32; rr += 8)
    out[(size_t)(c0 + rr) * R + r0 + tx] = t[tx][rr];
}

// ---------------------------------------------------------------------------
// MFMA GEMM: C[M][N] = A[M][K] * B[N][K]^T, all bf16 inputs.
// 128x128 block tile, 4 waves (2x2), each wave 64x64 = 4x4 MFMA 16x16x32.
// LDS rows padded to 40 shorts (80 B = 20 banks -> 2-way max conflicts).
// ---------------------------------------------------------------------------
#define EPI_NONE     0
#define EPI_SPLIT    1
#define EPI_SCALE    2
#define EPI_BIAS_RES 3
#define LDST 40

template<typename TC, typename TR, int EPI>
__global__ __launch_bounds__(256, 2) void gemm_mfma(
    const bfu* __restrict__ A, const bfu* __restrict__ B,
    TC* __restrict__ C, TC* __restrict__ C2,
    const float* __restrict__ bias, const TR* __restrict__ res,
    float scale, int N, int K, int lda, int ldb, int ldc,
    long long sA, long long sB, long long sC)
{
  const int bz = blockIdx.z;
  A += (size_t)bz * sA;
  B += (size_t)bz * sB;
  const size_t coff = (size_t)bz * sC;

  __shared__ __align__(16) short As[128 * LDST];
  __shared__ __align__(16) short Bs[128 * LDST];

  const int tid = threadIdx.x;
  const int lane = tid & 63, w = tid >> 6;
  const int m0 = blockIdx.y * 128, n0 = blockIdx.x * 128;
  const int wm = (w & 1) * 64, wn = (w >> 1) * 64;
  const int fr = lane & 15, quad = lane >> 4;

  f32x4 acc[4][4];
  #pragma unroll
  for (int i = 0; i < 4; ++i)
    #pragma unroll
    for (int j = 0; j < 4; ++j)
      #pragma unroll
      for (int r = 0; r < 4; ++r) acc[i][j][r] = 0.f;

  for (int k0 = 0; k0 < K; k0 += 32){
    #pragma unroll
    for (int i = 0; i < 2; ++i){
      const int ch = tid + 256 * i;             // 512 16B-chunks per tile
      const int r = ch >> 2, c = ch & 3;
      *(uint4*)&As[r * LDST + c * 8] =
          *(const uint4*)(A + (size_t)(m0 + r) * lda + k0 + c * 8);
      *(uint4*)&Bs[r * LDST + c * 8] =
          *(const uint4*)(B + (size_t)(n0 + r) * ldb + k0 + c * 8);
    }
    __syncthreads();
    bf16x8 af[4], bf[4];
    #pragma unroll
    for (int i = 0; i < 4; ++i)
      af[i] = *(const bf16x8*)&As[(wm + i * 16 + fr) * LDST + quad * 8];
    #pragma unroll
    for (int j = 0; j < 4; ++j)
      bf[j] = *(const bf16x8*)&Bs[(wn + j * 16 + fr) * LDST + quad * 8];
    #pragma unroll
    for (int i = 0; i < 4; ++i)
      #pragma unroll
      for (int j = 0; j < 4; ++j)
        acc[i][j] = __builtin_amdgcn_mfma_f32_16x16x32_bf16(af[i], bf[j], acc[i][j], 0, 0, 0);
    __syncthreads();
  }

  // C/D layout: col = lane&15, row = quad*4 + reg
  TC* Cp = C + coff;
  #pragma unroll
  for (int i = 0; i < 4; ++i){
    #pragma unroll
    for (int r = 0; r < 4; ++r){
      const int cm = m0 + wm + i * 16 + quad * 4 + r;
      #pragma unroll
      for (int j = 0; j < 4; ++j){
        const int cn = n0 + wn + j * 16 + fr;
        float v = acc[i][j][r];
        if (EPI == EPI_SCALE)    v *= scale;
        if (EPI == EPI_BIAS_RES) v = v + bias[cn] + loadE(&res[coff + (size_t)cm * ldc + cn]);
        if (EPI == EPI_SPLIT){
          const int half = N >> 1;
          if (cn < half) storeE(&C [(size_t)cm * half + cn],          v);
          else           storeE(&C2[(size_t)cm * half + (cn - half)], v);
        } else {
          storeE(&Cp[(size_t)cm * ldc + cn], v);
        }
      }
    }
  }
}

// ---------------------------------------------------------------------------
// Fused MLP1 + exact GeLU (MFMA): act = (A@w1T[a]+b1a) * gelu(A@w1T[g]+b1g).
// ---------------------------------------------------------------------------
__global__ __launch_bounds__(256, 1) void mlp1_mfma(
    const bfu* __restrict__ A, const bfu* __restrict__ B,  // B = w1T [4096][512]
    const float* __restrict__ b1, bfu* __restrict__ act)
{
  __shared__ __align__(16) short As[128 * LDST];
  __shared__ __align__(16) short Ba[128 * LDST];
  __shared__ __align__(16) short Bg[128 * LDST];

  const int tid = threadIdx.x;
  const int lane = tid & 63, w = tid >> 6;
  const int m0 = blockIdx.y * 128, n0 = blockIdx.x * 128;
  const int wm = (w & 1) * 64, wn = (w >> 1) * 64;
  const int fr = lane & 15, quad = lane >> 4;

  f32x4 acca[4][4], accg[4][4];
  #pragma unroll
  for (int i = 0; i < 4; ++i)
    #pragma unroll
    for (int j = 0; j < 4; ++j)
      #pragma unroll
      for (int r = 0; r < 4; ++r){ acca[i][j][r] = 0.f; accg[i][j][r] = 0.f; }

  for (int k0 = 0; k0 < 512; k0 += 32){
    #pragma unroll
    for (int i = 0; i < 2; ++i){
      const int ch = tid + 256 * i;
      const int r = ch >> 2, c = ch & 3;
      *(uint4*)&As[r * LDST + c * 8] =
          *(const uint4*)(A + (size_t)(m0 + r) * 512 + k0 + c * 8);
      *(uint4*)&Ba[r * LDST + c * 8] =
          *(const uint4*)(B + (size_t)(n0 + r) * 512 + k0 + c * 8);
      *(uint4*)&Bg[r * LDST + c * 8] =
          *(const uint4*)(B + (size_t)(n0 + 2048 + r) * 512 + k0 + c * 8);
    }
    __syncthreads();
    bf16x8 af[4], ba[4], bg[4];
    #pragma unroll
    for (int i = 0; i < 4; ++i)
      af[i] = *(const bf16x8*)&As[(wm + i * 16 + fr) * LDST + quad * 8];
    #pragma unroll
    for (int j = 0; j < 4; ++j){
      ba[j] = *(const bf16x8*)&Ba[(wn + j * 16 + fr) * LDST + quad * 8];
      bg[j] = *(const bf16x8*)&Bg[(wn + j * 16 + fr) * LDST + quad * 8];
    }
    #pragma unroll
    for (int i = 0; i < 4; ++i)
      #pragma unroll
      for (int j = 0; j < 4; ++j){
        acca[i][j] = __builtin_amdgcn_mfma_f32_16x16x32_bf16(af[i], ba[j], acca[i][j], 0, 0, 0);
        accg[i][j] = __builtin_amdgcn_mfma_f32_16x16x32_bf16(af[i], bg[j], accg[i][j], 0, 0, 0);
      }
    __syncthreads();
  }

  #pragma unroll
  for (int i = 0; i < 4; ++i){
    #pragma unroll
    for (int r = 0; r < 4; ++r){
      const int cm = m0 + wm + i * 16 + quad * 4 + r;
      #pragma unroll
      for (int j = 0; j < 4; ++j){
        const int cn = n0 + wn + j * 16 + fr;
        const float a = acca[i][j][r] + b1[cn];
        const float g = accg[i][j][r] + b1[cn + 2048];
        const float ge = g * 0.5f * (1.0f + erff(g * 0.70710678118654752f));
        act[(size_t)cm * 2048 + cn] = f2bf(a * ge);
      }
    }
  }
}

// ---------------------------------------------------------------------------
// Row softmax over 2048 bf16 logits, in place.
// ---------------------------------------------------------------------------
__global__ __launch_bounds__(256) void softmax_kernel(bfu* __restrict__ sc){
  __shared__ float red[4];
  const int tid = threadIdx.x;
  const int lane = tid & 63, wv = tid >> 6;
  bfu* rp = sc + (size_t)blockIdx.x * NCTX;
  float x[8];
  #pragma unroll
  for (int j = 0; j < 8; ++j) x[j] = bf2f(rp[tid + (j << 8)]);
  float mx = x[0];
  #pragma unroll
  for (int j = 1; j < 8; ++j) mx = fmaxf(mx, x[j]);
  for (int o = 32; o; o >>= 1) mx = fmaxf(mx, __shfl_xor(mx, o, 64));
  if (lane == 0) red[wv] = mx;
  __syncthreads();
  mx = fmaxf(fmaxf(red[0], red[1]), fmaxf(red[2], red[3]));
  float sum = 0.f;
  #pragma unroll
  for (int j = 0; j < 8; ++j){ x[j] = __expf(x[j] - mx); sum += x[j]; }
  for (int o = 32; o; o >>= 1) sum += __shfl_xor(sum, o, 64);
  __syncthreads();
  if (lane == 0) red[wv] = sum;
  __syncthreads();
  sum = red[0] + red[1] + red[2] + red[3];
  const float inv = 1.0f / sum;
  #pragma unroll
  for (int j = 0; j < 8; ++j) rp[tid + (j << 8)] = f2bf(x[j] * inv);
}

// ---------------------------------------------------------------------------
// LayerNorm rows of 512 fp32 -> bf16.
// ---------------------------------------------------------------------------
__global__ __launch_bounds__(256) void ln_kernel(const float* __restrict__ in,
                                                 const float* __restrict__ g,
                                                 const float* __restrict__ b,
                                                 bfu* __restrict__ out){
  const int tid = threadIdx.x, lane = tid & 63, wv = tid >> 6;
  const size_t row = (size_t)blockIdx.x * 4 + wv;
  const float* rp = in + row * DIMV;
  float x[8];
  #pragma unroll
  for (int j = 0; j < 8; ++j) x[j] = rp[lane + (j << 6)];
  float s = 0.f;
  #pragma unroll
  for (int j = 0; j < 8; ++j) s += x[j];
  for (int o = 32; o; o >>= 1) s += __shfl_xor(s, o, 64);
  const float m = s * (1.0f / 512.0f);
  float s2 = 0.f;
  #pragma unroll
  for (int j = 0; j < 8; ++j){ const float d = x[j] - m; s2 = fmaf(d, d, s2); }
  for (int o = 32; o; o >>= 1) s2 += __shfl_xor(s2, o, 64);
  const float inv = 1.0f / sqrtf(s2 * (1.0f / 512.0f) + 1e-5f);
  bfu* op = out + row * DIMV;
  #pragma unroll
  for (int j = 0; j < 8; ++j){
    const int c = lane + (j << 6);
    op[c] = f2bf((x[j] - m) * inv * g[c] + b[c]);
  }
}

// ---------------------------------------------------------------------------
// Workspace (peak 117,473,280 B < proven 125.8 MB):
//   idx    @ 0          (32 KB)
//   emb_s  @ 32768      (25,165,824) \  act half (50,331,648) aliases
//   q_in   @ 25198592   (25,165,824) /  emb_s+q_in after wo GEMM
//   c_grp  @ 50364416   (8,388,608)  -> scores
//   k_grp  @ 58753024   (8,388,608)
//   v_grp  @ 67141632   (8,388,608)
//   vT     @ 75530240   (8,388,608)
//   qbuf   @ 83918848   (25,165,824) -> lnx
//   wT     @ 109084672  (8,388,608): wqT|wkvT|woT|w1T|w2T
// ---------------------------------------------------------------------------
extern "C" void kernel_launch(void* const* d_in, const int* in_sizes, int n_in,
                              void* d_out, int out_size, void* d_ws, size_t ws_size,
                              hipStream_t stream)
{
  (void)in_sizes; (void)n_in; (void)out_size;
  if (ws_size < 117473280ull) return;

  const float* pc    = (const float*)d_in[0];
  const float* pc2   = (const float*)d_in[1];
  const float* basis = (const float*)d_in[2];
  const float* pe_w  = (const float*)d_in[3];
  const float* pe_b  = (const float*)d_in[4];
  const float* lnq_g = (const float*)d_in[5];
  const float* lnq_b = (const float*)d_in[6];
  const float* lnc_g = (const float*)d_in[7];
  const float* lnc_b = (const float*)d_in[8];
  const float* wq    = (const float*)d_in[9];
  const float* wkv   = (const float*)d_in[10];
  const float* wo    = (const float*)d_in[11];
  const float* bo    = (const float*)d_in[12];
  const float* lnf_g = (const float*)d_in[13];
  const float* lnf_b = (const float*)d_in[14];
  const float* w1    = (const float*)d_in[15];
  const float* b1    = (const float*)d_in[16];
  const float* w2    = (const float*)d_in[17];
  const float* b2    = (const float*)d_in[18];
  float* xout = (float*)d_out;

  char* ws = (char*)d_ws;
  int* idxb   = (int*)(ws);
  bfu* emb_s  = (bfu*)(ws + 32768);
  bfu* q_in   = (bfu*)(ws + 25198592);
  bfu* c_grp  = (bfu*)(ws + 50364416);
  bfu* k_grp  = (bfu*)(ws + 58753024);
  bfu* v_grp  = (bfu*)(ws + 67141632);
  bfu* vT     = (bfu*)(ws + 75530240);
  bfu* qbuf   = (bfu*)(ws + 83918848);
  bfu* wqT    = (bfu*)(ws + 109084672);
  bfu* wkvT   = (bfu*)(ws + 109608960);
  bfu* woT    = (bfu*)(ws + 110657536);
  bfu* w1T    = (bfu*)(ws + 111181824);
  bfu* w2T    = (bfu*)(ws + 115376128);
  bfu* scores  = c_grp;
  bfu* attnout = q_in;
  bfu* lnx     = qbuf;
  bfu* actb    = emb_s;     // spans emb_s+q_in (one MLP half at a time)

  // 0. weight transposes (fp32 [K][N] -> bf16 [N][K])
  transp_kernel<float><<<dim3(16, 16, 1),  256, 0, stream>>>(wq,  wqT,  512,  512, 0, 0);
  transp_kernel<float><<<dim3(32, 16, 1),  256, 0, stream>>>(wkv, wkvT, 512, 1024, 0, 0);
  transp_kernel<float><<<dim3(16, 16, 1),  256, 0, stream>>>(wo,  woT,  512,  512, 0, 0);
  transp_kernel<float><<<dim3(128, 16, 1), 256, 0, stream>>>(w1,  w1T,  512, 4096, 0, 0);
  transp_kernel<float><<<dim3(16, 64, 1),  256, 0, stream>>>(w2,  w2T, 2048,  512, 0, 0);

  // 1. FPS (4 waves per batch, DPP argmax + single barrier merge)
  fps_kernel<<<NB, 256, 0, stream>>>(pc, idxb);

  // 2. latent embed -> emb_s (raw) + q_in (LN'd)
  embed_kernel<true, true><<<MROWS/16, 256, 0, stream>>>(
      pc, pc2, idxb, basis, pe_w, pe_b, lnq_g, lnq_b, emb_s, q_in, NLAT);

  // 3. q = q_in @ wq
  gemm_mfma<bfu, float, EPI_NONE><<<dim3(4, 192, 1), 256, 0, stream>>>(
      q_in, wqT, qbuf, nullptr, nullptr, nullptr, 1.0f,
      512, 512, 512, 512, 512, 0, 0, 0);

  // 4. per-group context pipeline
  for (int g = 0; g < NGRP; ++g){
    const int bt0 = g * GRP;
    embed_kernel<false, false><<<GROWS/16, 256, 0, stream>>>(
        pc + (size_t)bt0 * NCTX * 3, pc2 + (size_t)bt0 * NCTX * 3, nullptr,
        basis, pe_w, pe_b, lnc_g, lnc_b, nullptr, c_grp, NCTX);

    gemm_mfma<bfu, float, EPI_SPLIT><<<dim3(8, 64, 1), 256, 0, stream>>>(
        c_grp, wkvT, k_grp, v_grp, nullptr, nullptr, 1.0f,
        1024, 512, 512, 512, 512, 0, 0, 0);

    transp_kernel<bfu><<<dim3(16, 64, GRP), 256, 0, stream>>>(
        v_grp, vT, 2048, 512, 2048*512, 2048*512);

    // scores = (q @ k^T) * scale, bf16 (overwrites c_grp)
    gemm_mfma<bfu, float, EPI_SCALE><<<dim3(16, 4, GRP), 256, 0, stream>>>(
        qbuf + (size_t)bt0 * 262144, k_grp, scores, nullptr, nullptr, nullptr,
        0.044194173824159216f,
        2048, 512, 512, 512, 2048, 262144, 1048576, 1048576);

    softmax_kernel<<<GRP * 512, 256, 0, stream>>>(scores);

    // attnout = P @ V  (B = vT, [512][2048])
    gemm_mfma<bfu, float, EPI_NONE><<<dim3(4, 4, GRP), 256, 0, stream>>>(
        scores, vT, attnout + (size_t)bt0 * 262144, nullptr, nullptr, nullptr, 1.0f,
        512, 2048, 2048, 2048, 512, 1048576, 1048576, 262144);
  }

  // 5. x = attnout @ wo + bo + emb_s -> d_out (fp32)
  gemm_mfma<float, bfu, EPI_BIAS_RES><<<dim3(4, 192, 1), 256, 0, stream>>>(
      attnout, woT, xout, nullptr, bo, emb_s, 1.0f,
      512, 512, 512, 512, 512, 0, 0, 0);

  // 6. lnx = LN(x)
  ln_kernel<<<MROWS/4, 256, 0, stream>>>(xout, lnf_g, lnf_b, lnx);

  // 7/8. MLP in two row-halves (act buffer holds one half)
  for (int h = 0; h < 2; ++h){
    const size_t ro = (size_t)h * 12288;
    mlp1_mfma<<<dim3(16, 96, 1), 256, 0, stream>>>(
        lnx + ro * 512, w1T, b1, actb);
    gemm_mfma<float, float, EPI_BIAS_RES><<<dim3(4, 96, 1), 256, 0, stream>>>(
        actb, w2T, xout + ro * 512, nullptr, b2, xout + ro * 512, 1.0f,
        512, 2048, 2048, 2048, 512, 0, 0, 0);
  }
}

// Round 8
// 2138.898 us; speedup vs baseline: 1.2242x; 1.1665x over previous
//
#include <hip/hip_runtime.h>

// Problem constants
#define NB    16
#define NT    3
#define NCTX  2048
#define NLAT  512
#define DIMV  512
#define HALFD 256
#define NFEAT 51
#define NBT   48
#define MROWS 24576    // NBT*NLAT
#define GRP   6        // bt per context group
#define NGRP  8
#define GROWS 12288    // GRP*NCTX

typedef unsigned short bfu;   // bf16 storage as raw bits
typedef short bf16x8 __attribute__((ext_vector_type(8)));   // 8 bf16 = 4 VGPR
typedef float f32x4  __attribute__((ext_vector_type(4)));   // MFMA 16x16 acc
typedef float f32x2  __attribute__((ext_vector_type(2)));   // packed fp32 pair

__device__ __forceinline__ float bf2f(bfu u){ return __uint_as_float(((unsigned int)u) << 16); }
__device__ __forceinline__ bfu f2bf(float f){
  unsigned int u = __float_as_uint(f);
  u += 0x7FFFu + ((u >> 16) & 1u);          // RNE
  return (bfu)(u >> 16);
}
__device__ __forceinline__ float loadE(const float* p){ return *p; }
__device__ __forceinline__ float loadE(const bfu* p){ return bf2f(*p); }
__device__ __forceinline__ void storeE(float* p, float v){ *p = v; }
__device__ __forceinline__ void storeE(bfu* p, float v){ *p = f2bf(v); }
__device__ __forceinline__ bfu to_bfu(float f){ return f2bf(f); }
__device__ __forceinline__ bfu to_bfu(bfu u){ return u; }

// ---------------------------------------------------------------------------
// FPS (best-of-series R7 version): 4 waves per batch, 8 pts/lane, DPP in-wave
// argmax + single-barrier double-buffered cross-wave merge. Bit-exact numpy.
// ---------------------------------------------------------------------------
#define DPP_ARGMAX_STAGE(CTRL)                                                \
  {                                                                           \
    const int svb = __builtin_amdgcn_update_dpp(vb, vb, CTRL, 0xF, 0xF, false); \
    const int sib = __builtin_amdgcn_update_dpp(ib, ib, CTRL, 0xF, 0xF, false); \
    const float sv = __int_as_float(svb);                                     \
    const float cv = __int_as_float(vb);                                      \
    if (sv > cv || (sv == cv && sib < ib)){ vb = svb; ib = sib; }             \
  }

__global__ __launch_bounds__(256) void fps_kernel(const float* __restrict__ pc,
                                                  int* __restrict__ idx_out){
#pragma clang fp contract(off)
  __shared__ float4 cxy4[1024];   // (x0,x1,y0,y1) for pair (i0, i0+64)
  __shared__ f32x2  cz2[1024];    // (z0,z1)
  __shared__ float  mval[2][4];
  __shared__ int    midx[2][4];
  const int b = blockIdx.x, tid = threadIdx.x;
  const int lane = tid & 63, w = tid >> 6;
  const int base = w << 9;                        // wave owns [512w, 512w+512)
  const float* src = pc + (size_t)b * (NT * NCTX * 3);

  f32x2 dist[4];
  #pragma unroll
  for (int p = 0; p < 4; ++p){
    const int i0 = base + (p << 7) + lane;
    const int i1 = i0 + 64;
    const float x0 = src[i0*3+0], y0 = src[i0*3+1], z0 = src[i0*3+2];
    const float x1 = src[i1*3+0], y1 = src[i1*3+1], z1 = src[i1*3+2];
    cxy4[(w << 8) + (p << 6) + lane] = make_float4(x0, x1, y0, y1);
    f32x2 z; z[0] = z0; z[1] = z1;
    cz2[(w << 8) + (p << 6) + lane] = z;
    dist[p][0] = 1e10f; dist[p][1] = 1e10f;
  }
  if (tid == 0) idx_out[b * NLAT] = 0;
  __syncthreads();

  int last = 0;
  for (int step = 1; step < NLAT; ++step){
    const int lw = last >> 9, lo = last & 511;
    const int li = (lw << 8) + ((lo >> 7) << 6) + (lo & 63);
    const int slot = (lo >> 6) & 1;
    const float4 la = cxy4[li];
    const f32x2  lc = cz2[li];
    const float lx = slot ? la.y : la.x;
    const float ly = slot ? la.w : la.z;
    const float lz = slot ? lc[1] : lc[0];

    float bv[2] = {-1.f, -1.f};
    int   bi[2] = {0, 0};
    #pragma unroll
    for (int p = 0; p < 4; ++p){
      const int c = p & 1;
      const float4 a = cxy4[(w << 8) + (p << 6) + lane];
      const f32x2  z = cz2[(w << 8) + (p << 6) + lane];
      f32x2 dx; dx[0] = a.x - lx; dx[1] = a.y - lx;
      f32x2 dy; dy[0] = a.z - ly; dy[1] = a.w - ly;
      f32x2 dz; dz[0] = z[0] - lz; dz[1] = z[1] - lz;
      const f32x2 d = (dx*dx + dy*dy) + dz*dz;    // contract(off): exact numpy
      f32x2 nd;
      nd[0] = fminf(dist[p][0], d[0]);
      nd[1] = fminf(dist[p][1], d[1]);
      dist[p] = nd;
      const int i0 = base + (p << 7) + lane;
      if (nd[0] > bv[c]){ bv[c] = nd[0]; bi[c] = i0; }
      if (nd[1] > bv[c]){ bv[c] = nd[1]; bi[c] = i0 + 64; }
    }
    if (bv[1] > bv[0] || (bv[1] == bv[0] && bi[1] < bi[0])){ bv[0] = bv[1]; bi[0] = bi[1]; }

    int vb = __float_as_int(bv[0]);
    int ib = bi[0];
    DPP_ARGMAX_STAGE(0x111)   // row_shr:1
    DPP_ARGMAX_STAGE(0x112)   // row_shr:2
    DPP_ARGMAX_STAGE(0x114)   // row_shr:4
    DPP_ARGMAX_STAGE(0x118)   // row_shr:8
    DPP_ARGMAX_STAGE(0x142)   // row_bcast:15
    DPP_ARGMAX_STAGE(0x143)   // row_bcast:31

    const int par = step & 1;
    if (lane == 63){ mval[par][w] = __int_as_float(vb); midx[par][w] = ib; }
    __syncthreads();
    float fv = mval[par][0]; int fi = midx[par][0];
    #pragma unroll
    for (int q = 1; q < 4; ++q){
      const float qv = mval[par][q]; const int qi = midx[par][q];
      if (qv > fv || (qv == fv && qi < fi)){ fv = qv; fi = qi; }
    }
    last = fi;
    if (tid == 0) idx_out[b * NLAT + step] = fi;
  }
}

// ---------------------------------------------------------------------------
// Fused (gather) + point_embed x2 + layernorm -> bf16. 16 points / block.
// ---------------------------------------------------------------------------
template<bool GATHER, bool WRITE_EMB>
__global__ __launch_bounds__(256) void embed_kernel(
    const float* __restrict__ pc, const float* __restrict__ pc2,
    const int* __restrict__ idx,
    const float* __restrict__ basis, const float* __restrict__ pe_w,
    const float* __restrict__ pe_b,
    const float* __restrict__ ln_g, const float* __restrict__ ln_b,
    bfu* __restrict__ emb, bfu* __restrict__ lnout, int nppbt)
{
  __shared__ float feat[2][16][NFEAT + 1];
  __shared__ float outb[16][DIMV];
  const int tid = threadIdx.x;
  const int p0 = blockIdx.x << 4;

  if (tid < 32){
    const int s = tid >> 4, p = tid & 15;
    const int gp = p0 + p;
    const int bt = gp / nppbt;
    const int n  = gp - bt * nppbt;
    const int bb = bt / NT;
    const int srcn = GATHER ? idx[bb * NLAT + n] : n;
    const float* sp = (s ? pc2 : pc) + ((size_t)bt * NCTX + srcn) * 3;
    const float x0 = sp[0], x1 = sp[1], x2 = sp[2];
    #pragma unroll
    for (int e = 0; e < 24; ++e){
      const float pr = __fadd_rn(__fadd_rn(__fmul_rn(x0, basis[e]),
                                           __fmul_rn(x1, basis[24 + e])),
                                 __fmul_rn(x2, basis[48 + e]));
      feat[s][p][e]      = sinf(pr);
      feat[s][p][24 + e] = cosf(pr);
    }
    feat[s][p][48] = x0; feat[s][p][49] = x1; feat[s][p][50] = x2;
  }
  __syncthreads();

  {
    float w[NFEAT];
    #pragma unroll
    for (int k = 0; k < NFEAT; ++k) w[k] = pe_w[k * HALFD + tid];
    const float bv = pe_b[tid];
    #pragma unroll
    for (int half = 0; half < 2; ++half){
      for (int p = 0; p < 16; ++p){
        float acc = bv;
        #pragma unroll
        for (int k = 0; k < NFEAT; ++k) acc = fmaf(feat[half][p][k], w[k], acc);
        outb[p][half * HALFD + tid] = acc;
      }
    }
  }
  __syncthreads();

  const int lane = tid & 63, wv = tid >> 6;
  for (int pp = 0; pp < 4; ++pp){
    const int p = (wv << 2) + pp;
    const size_t gp = (size_t)p0 + p;
    float x[8];
    #pragma unroll
    for (int j = 0; j < 8; ++j) x[j] = outb[p][lane + (j << 6)];
    float s = 0.f;
    #pragma unroll
    for (int j = 0; j < 8; ++j) s += x[j];
    for (int o = 32; o; o >>= 1) s += __shfl_xor(s, o, 64);
    const float m = s * (1.0f / 512.0f);
    float s2 = 0.f;
    #pragma unroll
    for (int j = 0; j < 8; ++j){ const float d = x[j] - m; s2 = fmaf(d, d, s2); }
    for (int o = 32; o; o >>= 1) s2 += __shfl_xor(s2, o, 64);
    const float inv = 1.0f / sqrtf(s2 * (1.0f / 512.0f) + 1e-5f);
    #pragma unroll
    for (int j = 0; j < 8; ++j){
      const int c = lane + (j << 6);
      const float r = (x[j] - m) * inv * ln_g[c] + ln_b[c];
      const size_t o2 = gp * DIMV + c;
      if (WRITE_EMB) emb[o2] = f2bf(x[j]);
      lnout[o2] = f2bf(r);
    }
  }
}

// ---------------------------------------------------------------------------
// Tiled transpose: in [R][C] (fp32 or bf16) -> out bf16 [C][R]. 32x32 tiles.
// ---------------------------------------------------------------------------
template<typename TIN>
__global__ __launch_bounds__(256) void transp_kernel(
    const TIN* __restrict__ in, bfu* __restrict__ out, int R, int C,
    long long sIn, long long sOut)
{
  __shared__ bfu t[32][33];
  in  += (size_t)blockIdx.z * sIn;
  out += (size_t)blockIdx.z * sOut;
  const int c0 = blockIdx.x * 32, r0 = blockIdx.y * 32;
  const int tx = threadIdx.x & 31, ty = threadIdx.x >> 5;
  #pragma unroll
  for (int rr = ty; rr < 32; rr += 8)
    t[rr][tx] = to_bfu(in[(size_t)(r0 + rr) * C + c0 + tx]);
  __syncthreads();
  #pragma unroll
  for (int rr = ty; rr < 32; rr += 8)
    out[(size_t)(c0 + rr) * R + r0 + tx] = t[tx][rr];
}

// ---------------------------------------------------------------------------
// MFMA GEMM: C[M][N] = A[M][K] * B[N][K]^T, bf16 inputs.
// Tile = (FH*32) x (FH*32): FH=4 -> 128x128 (4x4 frags/wave), FH=2 -> 64x64
// (2x2 frags/wave, for low-M/N batched GEMMs needing block-count occupancy).
// 4 waves in 2x2 grid. LDS rows padded to 40 shorts (2-way max conflicts).
// ---------------------------------------------------------------------------
#define EPI_NONE     0
#define EPI_SPLIT    1
#define EPI_SCALE    2
#define EPI_BIAS_RES 3
#define LDST 40

template<int FH, typename TC, typename TR, int EPI>
__global__ __launch_bounds__(256, 2) void gemm_mfma(
    const bfu* __restrict__ A, const bfu* __restrict__ B,
    TC* __restrict__ C, TC* __restrict__ C2,
    const float* __restrict__ bias, const TR* __restrict__ res,
    float scale, int N, int K, int lda, int ldb, int ldc,
    long long sA, long long sB, long long sC)
{
  constexpr int BT = FH * 32;              // block tile edge
  const int bz = blockIdx.z;
  A += (size_t)bz * sA;
  B += (size_t)bz * sB;
  const size_t coff = (size_t)bz * sC;

  __shared__ __align__(16) short As[BT * LDST];
  __shared__ __align__(16) short Bs[BT * LDST];

  const int tid = threadIdx.x;
  const int lane = tid & 63, w = tid >> 6;
  const int m0 = blockIdx.y * BT, n0 = blockIdx.x * BT;
  const int wm = (w & 1) * (FH * 16), wn = (w >> 1) * (FH * 16);
  const int fr = lane & 15, quad = lane >> 4;

  f32x4 acc[FH][FH];
  #pragma unroll
  for (int i = 0; i < FH; ++i)
    #pragma unroll
    for (int j = 0; j < FH; ++j)
      #pragma unroll
      for (int r = 0; r < 4; ++r) acc[i][j][r] = 0.f;

  for (int k0 = 0; k0 < K; k0 += 32){
    #pragma unroll
    for (int ch = tid; ch < BT * 4; ch += 256){   // 16B chunks per tile
      const int r = ch >> 2, c = ch & 3;
      *(uint4*)&As[r * LDST + c * 8] =
          *(const uint4*)(A + (size_t)(m0 + r) * lda + k0 + c * 8);
      *(uint4*)&Bs[r * LDST + c * 8] =
          *(const uint4*)(B + (size_t)(n0 + r) * ldb + k0 + c * 8);
    }
    __syncthreads();
    bf16x8 af[FH], bf[FH];
    #pragma unroll
    for (int i = 0; i < FH; ++i)
      af[i] = *(const bf16x8*)&As[(wm + i * 16 + fr) * LDST + quad * 8];
    #pragma unroll
    for (int j = 0; j < FH; ++j)
      bf[j] = *(const bf16x8*)&Bs[(wn + j * 16 + fr) * LDST + quad * 8];
    #pragma unroll
    for (int i = 0; i < FH; ++i)
      #pragma unroll
      for (int j = 0; j < FH; ++j)
        acc[i][j] = __builtin_amdgcn_mfma_f32_16x16x32_bf16(af[i], bf[j], acc[i][j], 0, 0, 0);
    __syncthreads();
  }

  // C/D layout: col = lane&15, row = quad*4 + reg
  TC* Cp = C + coff;
  #pragma unroll
  for (int i = 0; i < FH; ++i){
    #pragma unroll
    for (int r = 0; r < 4; ++r){
      const int cm = m0 + wm + i * 16 + quad * 4 + r;
      #pragma unroll
      for (int j = 0; j < FH; ++j){
        const int cn = n0 + wn + j * 16 + fr;
        float v = acc[i][j][r];
        if (EPI == EPI_SCALE)    v *= scale;
        if (EPI == EPI_BIAS_RES) v = v + bias[cn] + loadE(&res[coff + (size_t)cm * ldc + cn]);
        if (EPI == EPI_SPLIT){
          const int half = N >> 1;
          if (cn < half) storeE(&C [(size_t)cm * half + cn],          v);
          else           storeE(&C2[(size_t)cm * half + (cn - half)], v);
        } else {
          storeE(&Cp[(size_t)cm * ldc + cn], v);
        }
      }
    }
  }
}

// ---------------------------------------------------------------------------
// Fused MLP1 + exact GeLU (MFMA): act = (A@w1T[a]+b1a) * gelu(A@w1T[g]+b1g).
// ---------------------------------------------------------------------------
__global__ __launch_bounds__(256, 1) void mlp1_mfma(
    const bfu* __restrict__ A, const bfu* __restrict__ B,  // B = w1T [4096][512]
    const float* __restrict__ b1, bfu* __restrict__ act)
{
  __shared__ __align__(16) short As[128 * LDST];
  __shared__ __align__(16) short Ba[128 * LDST];
  __shared__ __align__(16) short Bg[128 * LDST];

  const int tid = threadIdx.x;
  const int lane = tid & 63, w = tid >> 6;
  const int m0 = blockIdx.y * 128, n0 = blockIdx.x * 128;
  const int wm = (w & 1) * 64, wn = (w >> 1) * 64;
  const int fr = lane & 15, quad = lane >> 4;

  f32x4 acca[4][4], accg[4][4];
  #pragma unroll
  for (int i = 0; i < 4; ++i)
    #pragma unroll
    for (int j = 0; j < 4; ++j)
      #pragma unroll
      for (int r = 0; r < 4; ++r){ acca[i][j][r] = 0.f; accg[i][j][r] = 0.f; }

  for (int k0 = 0; k0 < 512; k0 += 32){
    #pragma unroll
    for (int i = 0; i < 2; ++i){
      const int ch = tid + 256 * i;
      const int r = ch >> 2, c = ch & 3;
      *(uint4*)&As[r * LDST + c * 8] =
          *(const uint4*)(A + (size_t)(m0 + r) * 512 + k0 + c * 8);
      *(uint4*)&Ba[r * LDST + c * 8] =
          *(const uint4*)(B + (size_t)(n0 + r) * 512 + k0 + c * 8);
      *(uint4*)&Bg[r * LDST + c * 8] =
          *(const uint4*)(B + (size_t)(n0 + 2048 + r) * 512 + k0 + c * 8);
    }
    __syncthreads();
    bf16x8 af[4], ba[4], bg[4];
    #pragma unroll
    for (int i = 0; i < 4; ++i)
      af[i] = *(const bf16x8*)&As[(wm + i * 16 + fr) * LDST + quad * 8];
    #pragma unroll
    for (int j = 0; j < 4; ++j){
      ba[j] = *(const bf16x8*)&Ba[(wn + j * 16 + fr) * LDST + quad * 8];
      bg[j] = *(const bf16x8*)&Bg[(wn + j * 16 + fr) * LDST + quad * 8];
    }
    #pragma unroll
    for (int i = 0; i < 4; ++i)
      #pragma unroll
      for (int j = 0; j < 4; ++j){
        acca[i][j] = __builtin_amdgcn_mfma_f32_16x16x32_bf16(af[i], ba[j], acca[i][j], 0, 0, 0);
        accg[i][j] = __builtin_amdgcn_mfma_f32_16x16x32_bf16(af[i], bg[j], accg[i][j], 0, 0, 0);
      }
    __syncthreads();
  }

  #pragma unroll
  for (int i = 0; i < 4; ++i){
    #pragma unroll
    for (int r = 0; r < 4; ++r){
      const int cm = m0 + wm + i * 16 + quad * 4 + r;
      #pragma unroll
      for (int j = 0; j < 4; ++j){
        const int cn = n0 + wn + j * 16 + fr;
        const float a = acca[i][j][r] + b1[cn];
        const float g = accg[i][j][r] + b1[cn + 2048];
        const float ge = g * 0.5f * (1.0f + erff(g * 0.70710678118654752f));
        act[(size_t)cm * 2048 + cn] = f2bf(a * ge);
      }
    }
  }
}

// ---------------------------------------------------------------------------
// Row softmax over 2048 bf16 logits, in place.
// ---------------------------------------------------------------------------
__global__ __launch_bounds__(256) void softmax_kernel(bfu* __restrict__ sc){
  __shared__ float red[4];
  const int tid = threadIdx.x;
  const int lane = tid & 63, wv = tid >> 6;
  bfu* rp = sc + (size_t)blockIdx.x * NCTX;
  float x[8];
  #pragma unroll
  for (int j = 0; j < 8; ++j) x[j] = bf2f(rp[tid + (j << 8)]);
  float mx = x[0];
  #pragma unroll
  for (int j = 1; j < 8; ++j) mx = fmaxf(mx, x[j]);
  for (int o = 32; o; o >>= 1) mx = fmaxf(mx, __shfl_xor(mx, o, 64));
  if (lane == 0) red[wv] = mx;
  __syncthreads();
  mx = fmaxf(fmaxf(red[0], red[1]), fmaxf(red[2], red[3]));
  float sum = 0.f;
  #pragma unroll
  for (int j = 0; j < 8; ++j){ x[j] = __expf(x[j] - mx); sum += x[j]; }
  for (int o = 32; o; o >>= 1) sum += __shfl_xor(sum, o, 64);
  __syncthreads();
  if (lane == 0) red[wv] = sum;
  __syncthreads();
  sum = red[0] + red[1] + red[2] + red[3];
  const float inv = 1.0f / sum;
  #pragma unroll
  for (int j = 0; j < 8; ++j) rp[tid + (j << 8)] = f2bf(x[j] * inv);
}

// ---------------------------------------------------------------------------
// LayerNorm rows of 512 fp32 -> bf16.
// ---------------------------------------------------------------------------
__global__ __launch_bounds__(256) void ln_kernel(const float* __restrict__ in,
                                                 const float* __restrict__ g,
                                                 const float* __restrict__ b,
                                                 bfu* __restrict__ out){
  const int tid = threadIdx.x, lane = tid & 63, wv = tid >> 6;
  const size_t row = (size_t)blockIdx.x * 4 + wv;
  const float* rp = in + row * DIMV;
  float x[8];
  #pragma unroll
  for (int j = 0; j < 8; ++j) x[j] = rp[lane + (j << 6)];
  float s = 0.f;
  #pragma unroll
  for (int j = 0; j < 8; ++j) s += x[j];
  for (int o = 32; o; o >>= 1) s += __shfl_xor(s, o, 64);
  const float m = s * (1.0f / 512.0f);
  float s2 = 0.f;
  #pragma unroll
  for (int j = 0; j < 8; ++j){ const float d = x[j] - m; s2 = fmaf(d, d, s2); }
  for (int o = 32; o; o >>= 1) s2 += __shfl_xor(s2, o, 64);
  const float inv = 1.0f / sqrtf(s2 * (1.0f / 512.0f) + 1e-5f);
  bfu* op = out + row * DIMV;
  #pragma unroll
  for (int j = 0; j < 8; ++j){
    const int c = lane + (j << 6);
    op[c] = f2bf((x[j] - m) * inv * g[c] + b[c]);
  }
}

// ---------------------------------------------------------------------------
// Workspace (peak 121,667,584 B < proven 125,861,888):
//   idx    @ 0          (32 KB)
//   emb_s  @ 32768      (25,165,824) \  act half (50,331,648) aliases
//   q_in   @ 25198592   (25,165,824) /  emb_s+q_in (both dead at MLP)
//          q_in -> attnout after q GEMM
//   c_grp  @ 50364416   (12,582,912) -> scores (GRP=6)
//   k_grp  @ 62947328   (12,582,912) -> vT (k dead after scores; group loop
//                                          order: ...scores, softmax, transp, pv)
//   v_grp  @ 75530240   (12,582,912)
//   qbuf   @ 88113152   (25,165,824) -> lnx
//   wT     @ 113278976  (8,388,608): wqT|wkvT|woT|w1T|w2T
// ---------------------------------------------------------------------------
extern "C" void kernel_launch(void* const* d_in, const int* in_sizes, int n_in,
                              void* d_out, int out_size, void* d_ws, size_t ws_size,
                              hipStream_t stream)
{
  (void)in_sizes; (void)n_in; (void)out_size;
  if (ws_size < 121667584ull) return;

  const float* pc    = (const float*)d_in[0];
  const float* pc2   = (const float*)d_in[1];
  const float* basis = (const float*)d_in[2];
  const float* pe_w  = (const float*)d_in[3];
  const float* pe_b  = (const float*)d_in[4];
  const float* lnq_g = (const float*)d_in[5];
  const float* lnq_b = (const float*)d_in[6];
  const float* lnc_g = (const float*)d_in[7];
  const float* lnc_b = (const float*)d_in[8];
  const float* wq    = (const float*)d_in[9];
  const float* wkv   = (const float*)d_in[10];
  const float* wo    = (const float*)d_in[11];
  const float* bo    = (const float*)d_in[12];
  const float* lnf_g = (const float*)d_in[13];
  const float* lnf_b = (const float*)d_in[14];
  const float* w1    = (const float*)d_in[15];
  const float* b1    = (const float*)d_in[16];
  const float* w2    = (const float*)d_in[17];
  const float* b2    = (const float*)d_in[18];
  float* xout = (float*)d_out;

  char* ws = (char*)d_ws;
  int* idxb   = (int*)(ws);
  bfu* emb_s  = (bfu*)(ws + 32768);
  bfu* q_in   = (bfu*)(ws + 25198592);
  bfu* c_grp  = (bfu*)(ws + 50364416);
  bfu* k_grp  = (bfu*)(ws + 62947328);
  bfu* v_grp  = (bfu*)(ws + 75530240);
  bfu* qbuf   = (bfu*)(ws + 88113152);
  bfu* wqT    = (bfu*)(ws + 113278976);
  bfu* wkvT   = (bfu*)(ws + 113803264);
  bfu* woT    = (bfu*)(ws + 114851840);
  bfu* w1T    = (bfu*)(ws + 115376128);
  bfu* w2T    = (bfu*)(ws + 119570432);
  bfu* scores  = c_grp;     // after c consumed by kv
  bfu* vT      = k_grp;     // after k consumed by scores
  bfu* attnout = q_in;      // after q GEMM consumed q_in
  bfu* lnx     = qbuf;      // after attention consumed q
  bfu* actb    = emb_s;     // spans emb_s+q_in (one MLP half at a time)

  // 0. weight transposes (fp32 [K][N] -> bf16 [N][K])
  transp_kernel<float><<<dim3(16, 16, 1),  256, 0, stream>>>(wq,  wqT,  512,  512, 0, 0);
  transp_kernel<float><<<dim3(32, 16, 1),  256, 0, stream>>>(wkv, wkvT, 512, 1024, 0, 0);
  transp_kernel<float><<<dim3(16, 16, 1),  256, 0, stream>>>(wo,  woT,  512,  512, 0, 0);
  transp_kernel<float><<<dim3(128, 16, 1), 256, 0, stream>>>(w1,  w1T,  512, 4096, 0, 0);
  transp_kernel<float><<<dim3(16, 64, 1),  256, 0, stream>>>(w2,  w2T, 2048,  512, 0, 0);

  // 1. FPS
  fps_kernel<<<NB, 256, 0, stream>>>(pc, idxb);

  // 2. latent embed -> emb_s (raw) + q_in (LN'd)
  embed_kernel<true, true><<<MROWS/16, 256, 0, stream>>>(
      pc, pc2, idxb, basis, pe_w, pe_b, lnq_g, lnq_b, emb_s, q_in, NLAT);

  // 3. q = q_in @ wq
  gemm_mfma<4, bfu, float, EPI_NONE><<<dim3(4, 192, 1), 256, 0, stream>>>(
      q_in, wqT, qbuf, nullptr, nullptr, nullptr, 1.0f,
      512, 512, 512, 512, 512, 0, 0, 0);

  // 4. per-group context pipeline (GRP=6, 8 groups)
  for (int g = 0; g < NGRP; ++g){
    const int bt0 = g * GRP;
    embed_kernel<false, false><<<GROWS/16, 256, 0, stream>>>(
        pc + (size_t)bt0 * NCTX * 3, pc2 + (size_t)bt0 * NCTX * 3, nullptr,
        basis, pe_w, pe_b, lnc_g, lnc_b, nullptr, c_grp, NCTX);

    // kv = c @ wkv -> split k | v
    gemm_mfma<4, bfu, float, EPI_SPLIT><<<dim3(8, 96, 1), 256, 0, stream>>>(
        c_grp, wkvT, k_grp, v_grp, nullptr, nullptr, 1.0f,
        1024, 512, 512, 512, 512, 0, 0, 0);

    // scores = (q @ k^T) * scale (overwrites c_grp region)
    gemm_mfma<4, bfu, float, EPI_SCALE><<<dim3(16, 4, GRP), 256, 0, stream>>>(
        qbuf + (size_t)bt0 * 262144, k_grp, scores, nullptr, nullptr, nullptr,
        0.044194173824159216f,
        2048, 512, 512, 512, 2048, 262144, 1048576, 1048576);

    softmax_kernel<<<GRP * 512, 256, 0, stream>>>(scores);

    // vT = transpose(v) per bt (overwrites k_grp; k dead after scores)
    transp_kernel<bfu><<<dim3(16, 64, GRP), 256, 0, stream>>>(
        v_grp, vT, 2048, 512, 2048*512, 2048*512);

    // attnout = P @ V : 64x64 tiles -> (8,8,GRP) blocks for occupancy
    gemm_mfma<2, bfu, float, EPI_NONE><<<dim3(8, 8, GRP), 256, 0, stream>>>(
        scores, vT, attnout + (size_t)bt0 * 262144, nullptr, nullptr, nullptr, 1.0f,
        512, 2048, 2048, 2048, 512, 1048576, 1048576, 262144);
  }

  // 5. x = attnout @ wo + bo + emb_s -> d_out (fp32)
  gemm_mfma<4, float, bfu, EPI_BIAS_RES><<<dim3(4, 192, 1), 256, 0, stream>>>(
      attnout, woT, xout, nullptr, bo, emb_s, 1.0f,
      512, 512, 512, 512, 512, 0, 0, 0);

  // 6. lnx = LN(x)
  ln_kernel<<<MROWS/4, 256, 0, stream>>>(xout, lnf_g, lnf_b, lnx);

  // 7/8. MLP in two row-halves (act buffer holds one half)
  for (int h = 0; h < 2; ++h){
    const size_t ro = (size_t)h * 12288;
    mlp1_mfma<<<dim3(16, 96, 1), 256, 0, stream>>>(
        lnx + ro * 512, w1T, b1, actb);
    gemm_mfma<4, float, float, EPI_BIAS_RES><<<dim3(4, 96, 1), 256, 0, stream>>>(
        actb, w2T, xout + ro * 512, nullptr, b2, xout + ro * 512, 1.0f,
        512, 2048, 2048, 2048, 512, 0, 0, 0);
  }
}